// Round 3
// baseline (918.974 us; speedup 1.0000x reference)
//
#include <hip/hip_runtime.h>
#include <hip/hip_bf16.h>

// ---------------------------------------------------------------------------
// KascadeReuseAttention: B=2,S=4096,H=16,D=128, TILE=128, T=32, TOPK=7(+local)
// R3: attn waves own 16 q-rows (m=1) -> regs fit 128 budget, 4 waves/SIMD,
// grid 2048 blocks. Barrier-free, K/V direct from global (L2/LLC-warm),
// swapped-operand QK^T and PV, P per-wave in swizzled LDS.
// ---------------------------------------------------------------------------

typedef __bf16 bf16_t;
using bf16x8 = __attribute__((ext_vector_type(8))) __bf16;
using bf16x4 = __attribute__((ext_vector_type(4))) __bf16;
using f32x4  = __attribute__((ext_vector_type(4))) float;

typedef const __attribute__((address_space(1))) void* gas_ptr;
typedef __attribute__((address_space(3))) void* las_ptr;

__device__ __forceinline__ void async_copy16(const void* g, void* l) {
  __builtin_amdgcn_global_load_lds((gas_ptr)g, (las_ptr)l, 16, 0, 0);
}

__device__ __forceinline__ f32x4 mfma16x16x32(bf16x8 a, bf16x8 b, f32x4 c) {
  return __builtin_amdgcn_mfma_f32_16x16x32_bf16(a, b, c, 0, 0, 0);
}

// ---------------- elementwise f32 -> bf16 (vectorized) ----------------------
__global__ void cvt_f32_bf16(const float* __restrict__ X, bf16_t* __restrict__ Y) {
  int idx = blockIdx.x * 256 + threadIdx.x;
  float4 v = ((const float4*)X)[idx];
  bf16x4 r;
  r.x = (bf16_t)v.x; r.y = (bf16_t)v.y; r.z = (bf16_t)v.z; r.w = (bf16_t)v.w;
  ((bf16x4*)Y)[idx] = r;
}

// ---------------- weight transpose + convert: W[2048][2048] f32 -> Wt[n][k] bf16
__global__ void wtrans(const float* __restrict__ W, bf16_t* __restrict__ Wt) {
  __shared__ bf16_t t[64][66];
  const int r0 = blockIdx.x * 64, c0 = blockIdx.y * 64;
  const int tx = threadIdx.x & 63, ty = threadIdx.x >> 6;
  #pragma unroll
  for (int i = 0; i < 16; ++i) {
    int r = ty + 4 * i;
    t[r][tx] = (bf16_t)W[(size_t)(r0 + r) * 2048 + c0 + tx];
  }
  __syncthreads();
  #pragma unroll
  for (int i = 0; i < 16; ++i) {
    int n = ty + 4 * i;
    Wt[(size_t)(c0 + n) * 2048 + r0 + tx] = t[tx][n];
  }
}

// ---------------- GEMM: C[8192][2048] = A[8192][2048] * Bt[2048][2048]^T ----
__global__ __launch_bounds__(256, 2) void gemm_bt(
    const bf16_t* __restrict__ A, const bf16_t* __restrict__ Bt,
    float* __restrict__ Cf, bf16_t* __restrict__ Cq, int mode)
{
  __shared__ bf16_t lA[128 * 32];
  __shared__ bf16_t lB[128 * 32];
  const int bm = blockIdx.x * 128, bn = blockIdx.y * 128;
  const int tid = threadIdx.x;
  const int w = tid >> 6, l = tid & 63;
  const int wr = w >> 1, wc = w & 1;
  const int fr = l & 15, g4 = l >> 4;
  const int srow = l >> 2, scol = (l & 3) * 8;

  f32x4 acc[4][4];
  #pragma unroll
  for (int m = 0; m < 4; ++m)
    #pragma unroll
    for (int n = 0; n < 4; ++n) acc[m][n] = (f32x4){0.f, 0.f, 0.f, 0.f};

  for (int kt = 0; kt < 2048; kt += 32) {
    #pragma unroll
    for (int i = 0; i < 2; ++i) {
      int blk = i * 4 + w;
      int row = blk * 16 + srow;
      async_copy16(A  + (size_t)(bm + row) * 2048 + kt + scol, (char*)lA + blk * 1024);
      async_copy16(Bt + (size_t)(bn + row) * 2048 + kt + scol, (char*)lB + blk * 1024);
    }
    __syncthreads();
    bf16x8 af[4], bfq[4];
    #pragma unroll
    for (int m = 0; m < 4; ++m)
      af[m] = *(const bf16x8*)&lA[(wr * 64 + m * 16 + fr) * 32 + g4 * 8];
    #pragma unroll
    for (int n = 0; n < 4; ++n)
      bfq[n] = *(const bf16x8*)&lB[(wc * 64 + n * 16 + fr) * 32 + g4 * 8];
    #pragma unroll
    for (int m = 0; m < 4; ++m)
      #pragma unroll
      for (int n = 0; n < 4; ++n)
        acc[m][n] = mfma16x16x32(af[m], bfq[n], acc[m][n]);
    __syncthreads();
  }

  #pragma unroll
  for (int m = 0; m < 4; ++m)
    #pragma unroll
    for (int n = 0; n < 4; ++n)
      #pragma unroll
      for (int j = 0; j < 4; ++j) {
        int row = bm + wr * 64 + m * 16 + g4 * 4 + j;
        int col = bn + wc * 64 + n * 16 + fr;
        if (mode == 0) {
          Cf[(size_t)row * 2048 + col] = acc[m][n][j];
        } else {
          int b = row >> 12, s = row & 4095, h = col >> 7, d = col & 127;
          Cq[(((size_t)(b * 16 + h)) * 4096 + s) * 128 + d] = (bf16_t)acc[m][n][j];
        }
      }
}

// ---------------- RoPE in place on Q,K [BH=32][S=4096][D=128] bf16 ----------
__global__ void rope_kernel(bf16_t* __restrict__ Q, bf16_t* __restrict__ K,
                            const float* __restrict__ cosT, const float* __restrict__ sinT)
{
  int gid = blockIdx.x * 4 + (threadIdx.x >> 6);
  int i = threadIdx.x & 63;
  bf16_t* p = ((gid < 131072) ? Q : K) + (size_t)(gid & 131071) * 128;
  int s = gid & 4095;
  float c = cosT[s * 64 + i], sn = sinT[s * 64 + i];
  float x0 = (float)p[i], x1 = (float)p[i + 64];
  p[i]      = (bf16_t)(x0 * c - x1 * sn);
  p[i + 64] = (bf16_t)(x1 * c + x0 * sn);
}

// ---------------- V transpose: [BH][S][D] -> [BH][D][S] bf16 ----------------
__global__ void vtrans(const bf16_t* __restrict__ Vf, bf16_t* __restrict__ Vt)
{
  __shared__ bf16_t t[128][132];
  const int bh = blockIdx.x, s0 = blockIdx.y * 128;
  const int c = threadIdx.x & 127, half = threadIdx.x >> 7;
  for (int i = 0; i < 64; ++i) {
    int r = half + 2 * i;
    t[r][c] = Vf[((size_t)bh * 4096 + s0 + r) * 128 + c];
  }
  __syncthreads();
  for (int i = 0; i < 64; ++i) {
    int d = half + 2 * i;
    Vt[((size_t)bh * 128 + d) * 4096 + s0 + c] = t[c][d];
  }
}

// ---------------- sparse flash attention (barrier-free, m=1) ----------------
// block = (b,h,qt,half): 4 waves, each owns 16 q-rows independently.
// Swapped QK^T: S^T = mfma(Kfrag, Qfrag) -> lane col fr = q-row, regs hold
//   toks g4*4+j per 16-block n. Softmax: 2 shfl_xor (16,32) per stat; masked
//   logits written back into sc in place (no extra pv array).
// P packed bf16x4 -> per-wave 4KB LDS (XOR-swizzled 16B chunks).
// Swapped PV: O^T = mfma(V^T frag (global), P frag (LDS)).
__global__ __launch_bounds__(256, 4) void attn_kernel(
    const bf16_t* __restrict__ Qf, const bf16_t* __restrict__ Kf,
    const bf16_t* __restrict__ Vt, const int* __restrict__ anchors,
    bf16_t* __restrict__ outB)   // [B,S,2048] bf16
{
  __shared__ int tsel_s[8];
  __shared__ bf16_t Pbuf[4][2048];   // 4KB per wave
  const int orig = blockIdx.x;
  const int blk = (orig & 7) * 256 + (orig >> 3);   // XCD-chunked swizzle (2048%8==0)
  const int half = blk & 1, qt = (blk >> 1) & 31, h = (blk >> 6) & 15, b = blk >> 10;
  const int bh = b * 16 + h;
  const int tid = threadIdx.x, w = tid >> 6, l = tid & 63;
  const int fr = l & 15, g4 = l >> 4;
  const float scale = 0.08838834764831845f;   // 1/sqrt(128)

  const int* anc = anchors + ((size_t)bh * 32 + qt) * 7;
  if (tid < 7) tsel_s[tid] = anc[tid];
  if (tid == 7) tsel_s[7] = qt;
  __syncthreads();   // only barrier in the kernel

  const bf16_t* Qbase = Qf + (size_t)bh * 4096 * 128;
  const bf16_t* Kbase = Kf + (size_t)bh * 4096 * 128;
  const bf16_t* Vbase = Vt + (size_t)bh * 128 * 4096;
  char* P = (char*)&Pbuf[w][0];

  const int qrow = qt * 128 + half * 64 + w * 16 + fr;  // this lane's q (mfma col)

  // Q fragments (B-operand: col=q, k-chunk g4*8)
  bf16x8 aq[4];
  #pragma unroll
  for (int kc = 0; kc < 4; ++kc)
    aq[kc] = *(const bf16x8*)(Qbase + (size_t)qrow * 128 + kc * 32 + g4 * 8);

  float mrun = -1e30f, lrun = 0.f;
  f32x4 o[8];
  #pragma unroll
  for (int nd = 0; nd < 8; ++nd) o[nd] = (f32x4){0.f, 0.f, 0.f, 0.f};

  for (int t = 0; t < 8; ++t) {
    const int tb = tsel_s[t] * 128;

    // ---- S^T = K Q^T : sc[n], D rows = tok (g4*4+j), cols = q (fr) ----
    f32x4 sc[8];
    #pragma unroll
    for (int n = 0; n < 8; ++n) sc[n] = (f32x4){0.f, 0.f, 0.f, 0.f};
    #pragma unroll
    for (int kc = 0; kc < 4; ++kc) {
      bf16x8 kf[8];
      #pragma unroll
      for (int n = 0; n < 8; ++n)
        kf[n] = *(const bf16x8*)(Kbase + (size_t)(tb + n * 16 + fr) * 128 + kc * 32 + g4 * 8);
      #pragma unroll
      for (int n = 0; n < 8; ++n)
        sc[n] = mfma16x16x32(kf[n], aq[kc], sc[n]);
    }

    // ---- mask + scale in place, rowmax ----
    float rmax = -1e30f;
    #pragma unroll
    for (int n = 0; n < 8; ++n)
      #pragma unroll
      for (int j = 0; j < 4; ++j) {
        float lg = sc[n][j] * scale;
        int tok = tb + n * 16 + g4 * 4 + j;
        if (tok > qrow) lg = -1e10f;
        sc[n][j] = lg;
        rmax = fmaxf(rmax, lg);
      }
    rmax = fmaxf(rmax, __shfl_xor(rmax, 16));
    rmax = fmaxf(rmax, __shfl_xor(rmax, 32));
    float mnew = fmaxf(mrun, rmax);
    float alpha = __expf(mrun - mnew);
    float rsum = 0.f;
    #pragma unroll
    for (int n = 0; n < 8; ++n) {
      bf16x4 pk;
      #pragma unroll
      for (int j = 0; j < 4; ++j) {
        float p = __expf(sc[n][j] - mnew);
        rsum += p;
        pk[j] = (bf16_t)p;
      }
      int off = fr * 256 + ((((n << 1) | (g4 >> 1)) ^ (fr & 7)) << 4) + ((g4 & 1) << 3);
      *(bf16x4*)(P + off) = pk;
    }
    rsum += __shfl_xor(rsum, 16);
    rsum += __shfl_xor(rsum, 32);
    lrun = lrun * alpha + rsum;
    mrun = mnew;
    #pragma unroll
    for (int nd = 0; nd < 8; ++nd)
      #pragma unroll
      for (int j = 0; j < 4; ++j) o[nd][j] *= alpha;

    // ---- O^T += V^T P : A = V^T frag (global), B = P frag (LDS) ----
    #pragma unroll
    for (int kc = 0; kc < 4; ++kc) {
      bf16x8 av[8];
      #pragma unroll
      for (int nd = 0; nd < 8; ++nd)
        av[nd] = *(const bf16x8*)(Vbase + (size_t)(nd * 16 + fr) * 4096 + tb + kc * 32 + g4 * 8);
      bf16x8 bp = *(const bf16x8*)(P + fr * 256 + ((((kc << 2) | g4) ^ (fr & 7)) << 4));
      #pragma unroll
      for (int nd = 0; nd < 8; ++nd)
        o[nd] = mfma16x16x32(av[nd], bp, o[nd]);
    }
  }

  // ---- epilogue: normalize, pack rows into own LDS region, coalesced store
  {
    float inv = 1.0f / lrun;
    #pragma unroll
    for (int nd = 0; nd < 8; ++nd) {
      bf16x4 pk;
      #pragma unroll
      for (int j = 0; j < 4; ++j) pk[j] = (bf16_t)(o[nd][j] * inv);
      int off = fr * 256 + ((((nd << 1) | (g4 >> 1)) ^ (fr & 7)) << 4) + ((g4 & 1) << 3);
      *(bf16x4*)(P + off) = pk;
    }
  }
  #pragma unroll
  for (int i = 0; i < 4; ++i) {
    int r = i * 4 + g4;
    int off = r * 256 + ((fr ^ (r & 7)) << 4);
    bf16x8 vrow = *(const bf16x8*)(P + off);
    size_t gaddr = (((size_t)b * 4096 + qt * 128 + half * 64 + w * 16 + r) * 2048) + h * 128 + fr * 8;
    *(bf16x8*)(outB + gaddr) = vrow;
  }
}

// ---------------------------------------------------------------------------
// workspace layout (bytes)
#define OFF_XB   ((size_t)0)            // x bf16            [8192][2048]  32MB
#define OFF_WQT  ((size_t)33554432)     // wq^T bf16         [2048][2048]   8MB
#define OFF_WKT  ((size_t)41943040)
#define OFF_WVT  ((size_t)50331648)
#define OFF_WOT  ((size_t)58720256)
#define OFF_QF   ((size_t)67108864)     // Q bf16 [B,H,S,D]  32MB
#define OFF_KF   ((size_t)100663296)    // K bf16 [B,H,S,D]  32MB
#define OFF_VF   ((size_t)134217728)    // V bf16 [B,H,S,D]  32MB (reused: attn out [B,S,2048])
#define OFF_VT   ((size_t)167772160)    // V^T bf16 [B,H,D,S] 32MB

extern "C" void kernel_launch(void* const* d_in, const int* in_sizes, int n_in,
                              void* d_out, int out_size, void* d_ws, size_t ws_size,
                              hipStream_t stream) {
  (void)in_sizes; (void)n_in; (void)out_size; (void)ws_size;
  const float* x    = (const float*)d_in[0];
  const float* wq   = (const float*)d_in[1];
  const float* wk   = (const float*)d_in[2];
  const float* wv   = (const float*)d_in[3];
  const float* wo   = (const float*)d_in[4];
  const float* cosT = (const float*)d_in[5];
  const float* sinT = (const float*)d_in[6];
  const int*   anc  = (const int*)d_in[7];
  float* out = (float*)d_out;
  char* ws = (char*)d_ws;

  bf16_t* xb   = (bf16_t*)(ws + OFF_XB);
  bf16_t* wqt  = (bf16_t*)(ws + OFF_WQT);
  bf16_t* wkt  = (bf16_t*)(ws + OFF_WKT);
  bf16_t* wvt  = (bf16_t*)(ws + OFF_WVT);
  bf16_t* wot  = (bf16_t*)(ws + OFF_WOT);
  bf16_t* Qf   = (bf16_t*)(ws + OFF_QF);
  bf16_t* Kf   = (bf16_t*)(ws + OFF_KF);
  bf16_t* Vf   = (bf16_t*)(ws + OFF_VF);
  bf16_t* Vt   = (bf16_t*)(ws + OFF_VT);
  bf16_t* attnB = (bf16_t*)(ws + OFF_VF);  // alias: Vf dead after vtrans

  cvt_f32_bf16<<<16384, 256, 0, stream>>>(x, xb);
  wtrans<<<dim3(32, 32), 256, 0, stream>>>(wq, wqt);
  wtrans<<<dim3(32, 32), 256, 0, stream>>>(wk, wkt);
  wtrans<<<dim3(32, 32), 256, 0, stream>>>(wv, wvt);
  wtrans<<<dim3(32, 32), 256, 0, stream>>>(wo, wot);
  gemm_bt<<<dim3(64, 16), 256, 0, stream>>>(xb, wqt, nullptr, Qf, 1);
  gemm_bt<<<dim3(64, 16), 256, 0, stream>>>(xb, wkt, nullptr, Kf, 1);
  gemm_bt<<<dim3(64, 16), 256, 0, stream>>>(xb, wvt, nullptr, Vf, 1);
  rope_kernel<<<65536, 256, 0, stream>>>(Qf, Kf, cosT, sinT);
  vtrans<<<dim3(32, 32), 256, 0, stream>>>(Vf, Vt);
  attn_kernel<<<2048, 256, 0, stream>>>(Qf, Kf, Vt, anc, attnB);
  gemm_bt<<<dim3(64, 16), 256, 0, stream>>>(attnB, wot, out, nullptr, 0);
}

// Round 4
// 560.562 us; speedup vs baseline: 1.6394x; 1.6394x over previous
//
#include <hip/hip_runtime.h>
#include <hip/hip_bf16.h>

// ---------------------------------------------------------------------------
// KascadeReuseAttention: B=2,S=4096,H=16,D=128, TILE=128, T=32, TOPK=7(+local)
// R4: attn = LDS-shared K/V (1x read per block), KVBLK=64, double-buffered,
// issue-early/wait-late staging (T3 minimal 2-phase), 1 barrier per step.
// Swapped-operand QK^T / PV, packed P in per-wave swizzled LDS.
// ---------------------------------------------------------------------------

typedef __bf16 bf16_t;
using bf16x8 = __attribute__((ext_vector_type(8))) __bf16;
using bf16x4 = __attribute__((ext_vector_type(4))) __bf16;
using f32x4  = __attribute__((ext_vector_type(4))) float;

typedef const __attribute__((address_space(1))) void* gas_ptr;
typedef __attribute__((address_space(3))) void* las_ptr;

__device__ __forceinline__ void async_copy16(const void* g, void* l) {
  __builtin_amdgcn_global_load_lds((gas_ptr)g, (las_ptr)l, 16, 0, 0);
}

__device__ __forceinline__ f32x4 mfma16x16x32(bf16x8 a, bf16x8 b, f32x4 c) {
  return __builtin_amdgcn_mfma_f32_16x16x32_bf16(a, b, c, 0, 0, 0);
}

// ---------------- elementwise f32 -> bf16 (vectorized) ----------------------
__global__ void cvt_f32_bf16(const float* __restrict__ X, bf16_t* __restrict__ Y) {
  int idx = blockIdx.x * 256 + threadIdx.x;
  float4 v = ((const float4*)X)[idx];
  bf16x4 r;
  r.x = (bf16_t)v.x; r.y = (bf16_t)v.y; r.z = (bf16_t)v.z; r.w = (bf16_t)v.w;
  ((bf16x4*)Y)[idx] = r;
}

// ---------------- weight transpose + convert: W[2048][2048] f32 -> Wt[n][k] bf16
__global__ void wtrans(const float* __restrict__ W, bf16_t* __restrict__ Wt) {
  __shared__ bf16_t t[64][66];
  const int r0 = blockIdx.x * 64, c0 = blockIdx.y * 64;
  const int tx = threadIdx.x & 63, ty = threadIdx.x >> 6;
  #pragma unroll
  for (int i = 0; i < 16; ++i) {
    int r = ty + 4 * i;
    t[r][tx] = (bf16_t)W[(size_t)(r0 + r) * 2048 + c0 + tx];
  }
  __syncthreads();
  #pragma unroll
  for (int i = 0; i < 16; ++i) {
    int n = ty + 4 * i;
    Wt[(size_t)(c0 + n) * 2048 + r0 + tx] = t[tx][n];
  }
}

// ---------------- GEMM: C[8192][2048] = A[8192][2048] * Bt[2048][2048]^T ----
__global__ __launch_bounds__(256, 2) void gemm_bt(
    const bf16_t* __restrict__ A, const bf16_t* __restrict__ Bt,
    float* __restrict__ Cf, bf16_t* __restrict__ Cq, int mode)
{
  __shared__ bf16_t lA[128 * 32];
  __shared__ bf16_t lB[128 * 32];
  const int bm = blockIdx.x * 128, bn = blockIdx.y * 128;
  const int tid = threadIdx.x;
  const int w = tid >> 6, l = tid & 63;
  const int wr = w >> 1, wc = w & 1;
  const int fr = l & 15, g4 = l >> 4;
  const int srow = l >> 2, scol = (l & 3) * 8;

  f32x4 acc[4][4];
  #pragma unroll
  for (int m = 0; m < 4; ++m)
    #pragma unroll
    for (int n = 0; n < 4; ++n) acc[m][n] = (f32x4){0.f, 0.f, 0.f, 0.f};

  for (int kt = 0; kt < 2048; kt += 32) {
    #pragma unroll
    for (int i = 0; i < 2; ++i) {
      int blk = i * 4 + w;
      int row = blk * 16 + srow;
      async_copy16(A  + (size_t)(bm + row) * 2048 + kt + scol, (char*)lA + blk * 1024);
      async_copy16(Bt + (size_t)(bn + row) * 2048 + kt + scol, (char*)lB + blk * 1024);
    }
    __syncthreads();
    bf16x8 af[4], bfq[4];
    #pragma unroll
    for (int m = 0; m < 4; ++m)
      af[m] = *(const bf16x8*)&lA[(wr * 64 + m * 16 + fr) * 32 + g4 * 8];
    #pragma unroll
    for (int n = 0; n < 4; ++n)
      bfq[n] = *(const bf16x8*)&lB[(wc * 64 + n * 16 + fr) * 32 + g4 * 8];
    #pragma unroll
    for (int m = 0; m < 4; ++m)
      #pragma unroll
      for (int n = 0; n < 4; ++n)
        acc[m][n] = mfma16x16x32(af[m], bfq[n], acc[m][n]);
    __syncthreads();
  }

  #pragma unroll
  for (int m = 0; m < 4; ++m)
    #pragma unroll
    for (int n = 0; n < 4; ++n)
      #pragma unroll
      for (int j = 0; j < 4; ++j) {
        int row = bm + wr * 64 + m * 16 + g4 * 4 + j;
        int col = bn + wc * 64 + n * 16 + fr;
        if (mode == 0) {
          Cf[(size_t)row * 2048 + col] = acc[m][n][j];
        } else {
          int b = row >> 12, s = row & 4095, h = col >> 7, d = col & 127;
          Cq[(((size_t)(b * 16 + h)) * 4096 + s) * 128 + d] = (bf16_t)acc[m][n][j];
        }
      }
}

// ---------------- RoPE in place on Q,K [BH=32][S=4096][D=128] bf16 ----------
__global__ void rope_kernel(bf16_t* __restrict__ Q, bf16_t* __restrict__ K,
                            const float* __restrict__ cosT, const float* __restrict__ sinT)
{
  int gid = blockIdx.x * 4 + (threadIdx.x >> 6);
  int i = threadIdx.x & 63;
  bf16_t* p = ((gid < 131072) ? Q : K) + (size_t)(gid & 131071) * 128;
  int s = gid & 4095;
  float c = cosT[s * 64 + i], sn = sinT[s * 64 + i];
  float x0 = (float)p[i], x1 = (float)p[i + 64];
  p[i]      = (bf16_t)(x0 * c - x1 * sn);
  p[i + 64] = (bf16_t)(x1 * c + x0 * sn);
}

// ---------------- V transpose: [BH][S][D] -> [BH][D][S] bf16 ----------------
__global__ void vtrans(const bf16_t* __restrict__ Vf, bf16_t* __restrict__ Vt)
{
  __shared__ bf16_t t[128][132];
  const int bh = blockIdx.x, s0 = blockIdx.y * 128;
  const int c = threadIdx.x & 127, half = threadIdx.x >> 7;
  for (int i = 0; i < 64; ++i) {
    int r = half + 2 * i;
    t[r][c] = Vf[((size_t)bh * 4096 + s0 + r) * 128 + c];
  }
  __syncthreads();
  for (int i = 0; i < 64; ++i) {
    int d = half + 2 * i;
    Vt[((size_t)bh * 128 + d) * 4096 + s0 + c] = t[c][d];
  }
}

// ---------------- sparse flash attention (LDS-shared, pipelined) ------------
// block = (b,h,qt): 4 waves, wave owns 32 q-rows (m=0,1 x 16).
// 16 steps of KVBLK=64 toks (8 tiles x 2 halves). K[64][128] and V^T[128][64]
// staged in double-buffered LDS via global_load_lds (source-preswizzled,
// chunk ^= row&7); step t stages t+1 BEFORE computing t; one barrier/step.
// Swapped QK^T (S^T = K.Q), softmax 2x shfl, P packed bf16x4 to per-wave LDS,
// swapped PV (O^T = V^T.P).
__global__ __launch_bounds__(256, 2) void attn_kernel(
    const bf16_t* __restrict__ Qf, const bf16_t* __restrict__ Kf,
    const bf16_t* __restrict__ Vt, const int* __restrict__ anchors,
    bf16_t* __restrict__ outB)   // [B,S,2048] bf16
{
  __shared__ int tsel_s[8];
  __shared__ bf16_t Kl[2][8192];    // [64 tok][128 d], 16KB each
  __shared__ bf16_t Vl[2][8192];    // [128 d][64 tok], 16KB each
  __shared__ bf16_t Pbuf[4][2048];  // per-wave 4KB
  const int orig = blockIdx.x;
  const int blk = (orig & 7) * 128 + (orig >> 3);   // XCD-chunked swizzle
  const int qt = blk & 31, h = (blk >> 5) & 15, b = blk >> 9;
  const int bh = b * 16 + h;
  const int tid = threadIdx.x, w = tid >> 6, l = tid & 63;
  const int fr = l & 15, g4 = l >> 4;
  const float scale = 0.08838834764831845f;   // 1/sqrt(128)

  const int* anc = anchors + ((size_t)bh * 32 + qt) * 7;
  if (tid < 7) tsel_s[tid] = anc[tid];
  if (tid == 7) tsel_s[7] = qt;
  __syncthreads();

  const bf16_t* Qbase = Qf + (size_t)bh * 4096 * 128;
  const bf16_t* Kbase = Kf + (size_t)bh * 4096 * 128;
  const bf16_t* Vbase = Vt + (size_t)bh * 128 * 4096;
  char* P = (char*)&Pbuf[w][0];

  // stage K half-tile + V^T half-tile for token base tb2 into buffer p.
  // dest is lane-linear (c*16); source chunk pre-swizzled with ^(row&7).
  auto STAGE = [&](int tb2, int p) {
    const bf16_t* ksrc = Kbase + (size_t)tb2 * 128;
    const bf16_t* vsrc = Vbase + tb2;
    char* kd = (char*)&Kl[p][0];
    char* vd = (char*)&Vl[p][0];
    #pragma unroll
    for (int i = 0; i < 4; ++i) {
      int c = tid + i * 256;                 // 0..1023
      int kr = c >> 4, kcol = c & 15;        // K: 64 rows x 16 chunks
      async_copy16(ksrc + (size_t)kr * 128 + (size_t)((kcol ^ (kr & 7)) * 8),
                   kd + c * 16);
      int vr = c >> 3, vcol = c & 7;         // V^T: 128 rows x 8 chunks
      async_copy16(vsrc + (size_t)vr * 4096 + (size_t)((vcol ^ (vr & 7)) * 8),
                   vd + c * 16);
    }
  };

  // Q fragments (B-operand: col = q-row, k-chunk g4*8), direct from global
  bf16x8 aq[2][4];
  #pragma unroll
  for (int m = 0; m < 2; ++m) {
    int q = qt * 128 + w * 32 + m * 16 + fr;
    #pragma unroll
    for (int kc = 0; kc < 4; ++kc)
      aq[m][kc] = *(const bf16x8*)(Qbase + (size_t)q * 128 + kc * 32 + g4 * 8);
  }

  STAGE(tsel_s[0] * 128, 0);
  __syncthreads();   // drains vmcnt(0): step-0 buffers landed

  float mrun[2] = {-1e30f, -1e30f};
  float lrun[2] = {0.f, 0.f};
  f32x4 o[2][8];
  #pragma unroll
  for (int m = 0; m < 2; ++m)
    #pragma unroll
    for (int nd = 0; nd < 8; ++nd) o[m][nd] = (f32x4){0.f, 0.f, 0.f, 0.f};

  for (int s = 0; s < 16; ++s) {
    const int p = s & 1;
    const int tb2 = tsel_s[s >> 1] * 128 + (s & 1) * 64;
    // ---- issue next step's staging (flies under this step's compute) ----
    if (s < 15) {
      int s1 = s + 1;
      STAGE(tsel_s[s1 >> 1] * 128 + (s1 & 1) * 64, p ^ 1);
    }

    // ---- S^T = K Q^T from Kl[p]: sc[n][m], rows=tok(g4*4+j), cols=q(fr) ----
    f32x4 sc[4][2];
    #pragma unroll
    for (int n = 0; n < 4; ++n)
      #pragma unroll
      for (int m = 0; m < 2; ++m) sc[n][m] = (f32x4){0.f, 0.f, 0.f, 0.f};
    #pragma unroll
    for (int kc = 0; kc < 4; ++kc) {
      bf16x8 kf[4];
      #pragma unroll
      for (int n = 0; n < 4; ++n) {
        int r = n * 16 + fr;
        kf[n] = *(const bf16x8*)((const char*)&Kl[p][0] +
                 r * 256 + (((kc * 4 + g4) ^ (r & 7)) << 4));
      }
      #pragma unroll
      for (int n = 0; n < 4; ++n)
        #pragma unroll
        for (int m = 0; m < 2; ++m)
          sc[n][m] = mfma16x16x32(kf[n], aq[m][kc], sc[n][m]);
    }

    // ---- mask + online softmax per m; P -> per-wave LDS [32 q][64 tok] ----
    #pragma unroll
    for (int m = 0; m < 2; ++m) {
      const int qpos = qt * 128 + w * 32 + m * 16 + fr;
      const int q = m * 16 + fr;
      float rmax = -1e30f;
      #pragma unroll
      for (int n = 0; n < 4; ++n)
        #pragma unroll
        for (int j = 0; j < 4; ++j) {
          float lg = sc[n][m][j] * scale;
          int tok = tb2 + n * 16 + g4 * 4 + j;
          if (tok > qpos) lg = -1e10f;
          sc[n][m][j] = lg;
          rmax = fmaxf(rmax, lg);
        }
      rmax = fmaxf(rmax, __shfl_xor(rmax, 16));
      rmax = fmaxf(rmax, __shfl_xor(rmax, 32));
      float mnew = fmaxf(mrun[m], rmax);
      float alpha = __expf(mrun[m] - mnew);
      float rsum = 0.f;
      #pragma unroll
      for (int n = 0; n < 4; ++n) {
        bf16x4 pk;
        #pragma unroll
        for (int j = 0; j < 4; ++j) {
          float pe = __expf(sc[n][m][j] - mnew);
          rsum += pe;
          pk[j] = (bf16_t)pe;
        }
        int off = q * 128 + ((((n << 1) | (g4 >> 1)) ^ (q & 7)) << 4) + ((g4 & 1) << 3);
        *(bf16x4*)(P + off) = pk;
      }
      rsum += __shfl_xor(rsum, 16);
      rsum += __shfl_xor(rsum, 32);
      lrun[m] = lrun[m] * alpha + rsum;
      mrun[m] = mnew;
      #pragma unroll
      for (int nd = 0; nd < 8; ++nd)
        #pragma unroll
        for (int j = 0; j < 4; ++j) o[m][nd][j] *= alpha;
    }

    // ---- O^T += V^T P from Vl[p] + per-wave P ----
    #pragma unroll
    for (int kc2 = 0; kc2 < 2; ++kc2) {
      bf16x8 av[8];
      #pragma unroll
      for (int nd = 0; nd < 8; ++nd) {
        int r = nd * 16 + fr;
        av[nd] = *(const bf16x8*)((const char*)&Vl[p][0] +
                  r * 128 + (((kc2 * 4 + g4) ^ (r & 7)) << 4));
      }
      bf16x8 bp[2];
      #pragma unroll
      for (int m = 0; m < 2; ++m) {
        int q = m * 16 + fr;
        bp[m] = *(const bf16x8*)(P + q * 128 + ((((kc2 << 2) | g4) ^ (q & 7)) << 4));
      }
      #pragma unroll
      for (int nd = 0; nd < 8; ++nd)
        #pragma unroll
        for (int m = 0; m < 2; ++m)
          o[m][nd] = mfma16x16x32(av[nd], bp[m], o[m][nd]);
    }
    __syncthreads();   // drain next-step staging + all waves done with buf p
  }

  // ---- epilogue: normalize; per m: O^T -> LDS [16 q rows x 256B] -> store
  #pragma unroll
  for (int m = 0; m < 2; ++m) {
    float inv = 1.0f / lrun[m];
    #pragma unroll
    for (int nd = 0; nd < 8; ++nd) {
      bf16x4 pk;
      #pragma unroll
      for (int j = 0; j < 4; ++j) pk[j] = (bf16_t)(o[m][nd][j] * inv);
      int off = fr * 256 + ((((nd << 1) | (g4 >> 1)) ^ (fr & 7)) << 4) + ((g4 & 1) << 3);
      *(bf16x4*)(P + off) = pk;
    }
    #pragma unroll
    for (int i = 0; i < 4; ++i) {
      int r = i * 4 + g4;
      int off = r * 256 + ((fr ^ (r & 7)) << 4);
      bf16x8 vrow = *(const bf16x8*)(P + off);
      size_t gaddr = (((size_t)b * 4096 + qt * 128 + w * 32 + m * 16 + r) * 2048)
                     + h * 128 + fr * 8;
      *(bf16x8*)(outB + gaddr) = vrow;
    }
  }
}

// ---------------------------------------------------------------------------
// workspace layout (bytes)
#define OFF_XB   ((size_t)0)            // x bf16            [8192][2048]  32MB
#define OFF_WQT  ((size_t)33554432)     // wq^T bf16         [2048][2048]   8MB
#define OFF_WKT  ((size_t)41943040)
#define OFF_WVT  ((size_t)50331648)
#define OFF_WOT  ((size_t)58720256)
#define OFF_QF   ((size_t)67108864)     // Q bf16 [B,H,S,D]  32MB
#define OFF_KF   ((size_t)100663296)    // K bf16 [B,H,S,D]  32MB
#define OFF_VF   ((size_t)134217728)    // V bf16 [B,H,S,D]  32MB (reused: attn out)
#define OFF_VT   ((size_t)167772160)    // V^T bf16 [B,H,D,S] 32MB

extern "C" void kernel_launch(void* const* d_in, const int* in_sizes, int n_in,
                              void* d_out, int out_size, void* d_ws, size_t ws_size,
                              hipStream_t stream) {
  (void)in_sizes; (void)n_in; (void)out_size; (void)ws_size;
  const float* x    = (const float*)d_in[0];
  const float* wq   = (const float*)d_in[1];
  const float* wk   = (const float*)d_in[2];
  const float* wv   = (const float*)d_in[3];
  const float* wo   = (const float*)d_in[4];
  const float* cosT = (const float*)d_in[5];
  const float* sinT = (const float*)d_in[6];
  const int*   anc  = (const int*)d_in[7];
  float* out = (float*)d_out;
  char* ws = (char*)d_ws;

  bf16_t* xb   = (bf16_t*)(ws + OFF_XB);
  bf16_t* wqt  = (bf16_t*)(ws + OFF_WQT);
  bf16_t* wkt  = (bf16_t*)(ws + OFF_WKT);
  bf16_t* wvt  = (bf16_t*)(ws + OFF_WVT);
  bf16_t* wot  = (bf16_t*)(ws + OFF_WOT);
  bf16_t* Qf   = (bf16_t*)(ws + OFF_QF);
  bf16_t* Kf   = (bf16_t*)(ws + OFF_KF);
  bf16_t* Vf   = (bf16_t*)(ws + OFF_VF);
  bf16_t* Vt   = (bf16_t*)(ws + OFF_VT);
  bf16_t* attnB = (bf16_t*)(ws + OFF_VF);  // alias: Vf dead after vtrans

  cvt_f32_bf16<<<16384, 256, 0, stream>>>(x, xb);
  wtrans<<<dim3(32, 32), 256, 0, stream>>>(wq, wqt);
  wtrans<<<dim3(32, 32), 256, 0, stream>>>(wk, wkt);
  wtrans<<<dim3(32, 32), 256, 0, stream>>>(wv, wvt);
  wtrans<<<dim3(32, 32), 256, 0, stream>>>(wo, wot);
  gemm_bt<<<dim3(64, 16), 256, 0, stream>>>(xb, wqt, nullptr, Qf, 1);
  gemm_bt<<<dim3(64, 16), 256, 0, stream>>>(xb, wkt, nullptr, Kf, 1);
  gemm_bt<<<dim3(64, 16), 256, 0, stream>>>(xb, wvt, nullptr, Vf, 1);
  rope_kernel<<<65536, 256, 0, stream>>>(Qf, Kf, cosT, sinT);
  vtrans<<<dim3(32, 32), 256, 0, stream>>>(Vf, Vt);
  attn_kernel<<<1024, 256, 0, stream>>>(Qf, Kf, Vt, anc, attnB);
  gemm_bt<<<dim3(64, 16), 256, 0, stream>>>(attnB, wot, out, nullptr, 0);
}

// Round 5
// 479.026 us; speedup vs baseline: 1.9184x; 1.1702x over previous
//
#include <hip/hip_runtime.h>
#include <hip/hip_bf16.h>

// ---------------------------------------------------------------------------
// KascadeReuseAttention: B=2,S=4096,H=16,D=128, TILE=128, T=32, TOPK=7(+local)
// R5: attn skips fully-future tiles (weight==0), masks only the local tile,
// packed reg tile-list (LDS=80KB exact -> 2 blocks/CU), defer-max rescale,
// high-qt-first dispatch. V^T written directly by V-GEMM epilogue (no vtrans).
// ---------------------------------------------------------------------------

typedef __bf16 bf16_t;
using bf16x8 = __attribute__((ext_vector_type(8))) __bf16;
using bf16x4 = __attribute__((ext_vector_type(4))) __bf16;
using f32x4  = __attribute__((ext_vector_type(4))) float;

typedef const __attribute__((address_space(1))) void* gas_ptr;
typedef __attribute__((address_space(3))) void* las_ptr;

__device__ __forceinline__ void async_copy16(const void* g, void* l) {
  __builtin_amdgcn_global_load_lds((gas_ptr)g, (las_ptr)l, 16, 0, 0);
}

__device__ __forceinline__ f32x4 mfma16x16x32(bf16x8 a, bf16x8 b, f32x4 c) {
  return __builtin_amdgcn_mfma_f32_16x16x32_bf16(a, b, c, 0, 0, 0);
}

// ---------------- elementwise f32 -> bf16 (vectorized) ----------------------
__global__ void cvt_f32_bf16(const float* __restrict__ X, bf16_t* __restrict__ Y) {
  int idx = blockIdx.x * 256 + threadIdx.x;
  float4 v = ((const float4*)X)[idx];
  bf16x4 r;
  r.x = (bf16_t)v.x; r.y = (bf16_t)v.y; r.z = (bf16_t)v.z; r.w = (bf16_t)v.w;
  ((bf16x4*)Y)[idx] = r;
}

// ---------------- weight transpose + convert: W[2048][2048] f32 -> Wt[n][k] bf16
__global__ void wtrans(const float* __restrict__ W, bf16_t* __restrict__ Wt) {
  __shared__ bf16_t t[64][66];
  const int r0 = blockIdx.x * 64, c0 = blockIdx.y * 64;
  const int tx = threadIdx.x & 63, ty = threadIdx.x >> 6;
  #pragma unroll
  for (int i = 0; i < 16; ++i) {
    int r = ty + 4 * i;
    t[r][tx] = (bf16_t)W[(size_t)(r0 + r) * 2048 + c0 + tx];
  }
  __syncthreads();
  #pragma unroll
  for (int i = 0; i < 16; ++i) {
    int n = ty + 4 * i;
    Wt[(size_t)(c0 + n) * 2048 + r0 + tx] = t[tx][n];
  }
}

// ---------------- GEMM: C[8192][2048] = A[8192][2048] * Bt[2048][2048]^T ----
// mode 0: f32 C row-major. mode 1: bf16 [B,H,S,D]. mode 2: bf16 V^T [B,H,D,S].
__global__ __launch_bounds__(256, 2) void gemm_bt(
    const bf16_t* __restrict__ A, const bf16_t* __restrict__ Bt,
    float* __restrict__ Cf, bf16_t* __restrict__ Cq, int mode)
{
  __shared__ bf16_t lA[128 * 32];
  __shared__ bf16_t lB[128 * 32];
  const int bm = blockIdx.x * 128, bn = blockIdx.y * 128;
  const int tid = threadIdx.x;
  const int w = tid >> 6, l = tid & 63;
  const int wr = w >> 1, wc = w & 1;
  const int fr = l & 15, g4 = l >> 4;
  const int srow = l >> 2, scol = (l & 3) * 8;

  f32x4 acc[4][4];
  #pragma unroll
  for (int m = 0; m < 4; ++m)
    #pragma unroll
    for (int n = 0; n < 4; ++n) acc[m][n] = (f32x4){0.f, 0.f, 0.f, 0.f};

  for (int kt = 0; kt < 2048; kt += 32) {
    #pragma unroll
    for (int i = 0; i < 2; ++i) {
      int blk = i * 4 + w;
      int row = blk * 16 + srow;
      async_copy16(A  + (size_t)(bm + row) * 2048 + kt + scol, (char*)lA + blk * 1024);
      async_copy16(Bt + (size_t)(bn + row) * 2048 + kt + scol, (char*)lB + blk * 1024);
    }
    __syncthreads();
    bf16x8 af[4], bfq[4];
    #pragma unroll
    for (int m = 0; m < 4; ++m)
      af[m] = *(const bf16x8*)&lA[(wr * 64 + m * 16 + fr) * 32 + g4 * 8];
    #pragma unroll
    for (int n = 0; n < 4; ++n)
      bfq[n] = *(const bf16x8*)&lB[(wc * 64 + n * 16 + fr) * 32 + g4 * 8];
    #pragma unroll
    for (int m = 0; m < 4; ++m)
      #pragma unroll
      for (int n = 0; n < 4; ++n)
        acc[m][n] = mfma16x16x32(af[m], bfq[n], acc[m][n]);
    __syncthreads();
  }

  if (mode == 2) {
    // write V^T [BH*128 d][4096 s]: j-quad of rows s packs to one bf16x4 store
    #pragma unroll
    for (int m = 0; m < 4; ++m)
      #pragma unroll
      for (int n = 0; n < 4; ++n) {
        int colv = bn + wc * 64 + n * 16 + fr;
        int h_ = colv >> 7, d_ = colv & 127;
        int row0 = bm + wr * 64 + m * 16 + g4 * 4;
        int b_ = row0 >> 12, s0 = row0 & 4095;
        bf16x4 pk;
        #pragma unroll
        for (int j = 0; j < 4; ++j) pk[j] = (bf16_t)acc[m][n][j];
        *(bf16x4*)&Cq[(((size_t)(b_ * 16 + h_)) * 128 + d_) * 4096 + s0] = pk;
      }
    return;
  }

  #pragma unroll
  for (int m = 0; m < 4; ++m)
    #pragma unroll
    for (int n = 0; n < 4; ++n)
      #pragma unroll
      for (int j = 0; j < 4; ++j) {
        int row = bm + wr * 64 + m * 16 + g4 * 4 + j;
        int col = bn + wc * 64 + n * 16 + fr;
        if (mode == 0) {
          Cf[(size_t)row * 2048 + col] = acc[m][n][j];
        } else {
          int b = row >> 12, s = row & 4095, h = col >> 7, d = col & 127;
          Cq[(((size_t)(b * 16 + h)) * 4096 + s) * 128 + d] = (bf16_t)acc[m][n][j];
        }
      }
}

// ---------------- RoPE in place on Q,K [BH=32][S=4096][D=128] bf16 ----------
__global__ void rope_kernel(bf16_t* __restrict__ Q, bf16_t* __restrict__ K,
                            const float* __restrict__ cosT, const float* __restrict__ sinT)
{
  int gid = blockIdx.x * 4 + (threadIdx.x >> 6);
  int i = threadIdx.x & 63;
  bf16_t* p = ((gid < 131072) ? Q : K) + (size_t)(gid & 131071) * 128;
  int s = gid & 4095;
  float c = cosT[s * 64 + i], sn = sinT[s * 64 + i];
  float x0 = (float)p[i], x1 = (float)p[i + 64];
  p[i]      = (bf16_t)(x0 * c - x1 * sn);
  p[i + 64] = (bf16_t)(x1 * c + x0 * sn);
}

// ---------------- sparse flash attention (LDS-shared, pipelined, skip) ------
// block = (b,h,qt): 4 waves, wave owns 32 q-rows (m=0,1 x 16).
// Active tiles only (tsel <= qt; weight of future tiles is exactly 0),
// packed 5-bit list in a per-thread uint64 (no LDS list, no extra barrier).
// Steps of KVBLK=64 toks, double-buffered K/V in LDS (source-preswizzled
// chunk ^= row&7); step s stages s+1 before computing s; 1 barrier/step.
// Masking only when tsel == qt. Defer-max rescale (T13, thr=8).
__global__ __launch_bounds__(256, 2) void attn_kernel(
    const bf16_t* __restrict__ Qf, const bf16_t* __restrict__ Kf,
    const bf16_t* __restrict__ Vt, const int* __restrict__ anchors,
    bf16_t* __restrict__ outB)   // [B,S,2048] bf16
{
  __shared__ bf16_t Kl[2][8192];    // [64 tok][128 d] swizzled, 16KB each
  __shared__ bf16_t Vl[2][8192];    // [128 d][64 tok] swizzled, 16KB each
  __shared__ bf16_t Pbuf[4][2048];  // per-wave 4KB    (total LDS = 80KB exact)
  const int orig = blockIdx.x;
  const int blk = (orig & 7) * 128 + (orig >> 3);   // XCD-chunked swizzle
  const int qt = 31 - (blk & 31);                   // high-qt (long) blocks first
  const int h = (blk >> 5) & 15, b = blk >> 9;
  const int bh = b * 16 + h;
  const int tid = threadIdx.x, w = tid >> 6, l = tid & 63;
  const int fr = l & 15, g4 = l >> 4;
  const float scale = 0.08838834764831845f;   // 1/sqrt(128)

  // ---- build packed active-tile list (identical in every thread) ----
  const int* anc = anchors + ((size_t)bh * 32 + qt) * 7;
  unsigned long long pk = 0;
  int nt = 0;
  #pragma unroll
  for (int t = 0; t < 7; ++t) {
    int v = anc[t];
    if (v <= qt) { pk |= (unsigned long long)v << (5 * nt); ++nt; }
  }
  pk |= (unsigned long long)qt << (5 * nt); ++nt;   // local tile last
  const int NS = nt * 2;

  const bf16_t* Qbase = Qf + (size_t)bh * 4096 * 128;
  const bf16_t* Kbase = Kf + (size_t)bh * 4096 * 128;
  const bf16_t* Vbase = Vt + (size_t)bh * 128 * 4096;
  char* P = (char*)&Pbuf[w][0];

  auto STAGE = [&](int tb2, int p) {
    const bf16_t* ksrc = Kbase + (size_t)tb2 * 128;
    const bf16_t* vsrc = Vbase + tb2;
    char* kd = (char*)&Kl[p][0];
    char* vd = (char*)&Vl[p][0];
    #pragma unroll
    for (int i = 0; i < 4; ++i) {
      int c = tid + i * 256;                 // 0..1023
      int kr = c >> 4, kcol = c & 15;        // K: 64 rows x 16 chunks
      async_copy16(ksrc + (size_t)kr * 128 + (size_t)((kcol ^ (kr & 7)) * 8),
                   kd + c * 16);
      int vr = c >> 3, vcol = c & 7;         // V^T: 128 rows x 8 chunks
      async_copy16(vsrc + (size_t)vr * 4096 + (size_t)((vcol ^ (vr & 7)) * 8),
                   vd + c * 16);
    }
  };

  // Q fragments (B-operand: col = q-row, k-chunk g4*8), direct from global
  bf16x8 aq[2][4];
  #pragma unroll
  for (int m = 0; m < 2; ++m) {
    int q = qt * 128 + w * 32 + m * 16 + fr;
    #pragma unroll
    for (int kc = 0; kc < 4; ++kc)
      aq[m][kc] = *(const bf16x8*)(Qbase + (size_t)q * 128 + kc * 32 + g4 * 8);
  }

  STAGE((int)(pk & 31) * 128, 0);
  __syncthreads();   // step-0 buffers landed

  float mrun[2] = {-1e30f, -1e30f};
  float lrun[2] = {0.f, 0.f};
  f32x4 o[2][8];
  #pragma unroll
  for (int m = 0; m < 2; ++m)
    #pragma unroll
    for (int nd = 0; nd < 8; ++nd) o[m][nd] = (f32x4){0.f, 0.f, 0.f, 0.f};

  for (int s = 0; s < NS; ++s) {
    const int p = s & 1;
    const int ts = (int)((pk >> (5 * (s >> 1))) & 31);
    const bool domask = (ts == qt);
    // ---- issue next step's staging (flies under this step's compute) ----
    if (s + 1 < NS) {
      int s1 = s + 1;
      int ts1 = (int)((pk >> (5 * (s1 >> 1))) & 31);
      STAGE(ts1 * 128 + (s1 & 1) * 64, p ^ 1);
    }

    // ---- S^T = K Q^T from Kl[p]: sc[n][m], rows=tok(g4*4+j), cols=q(fr) ----
    f32x4 sc[4][2];
    #pragma unroll
    for (int n = 0; n < 4; ++n)
      #pragma unroll
      for (int m = 0; m < 2; ++m) sc[n][m] = (f32x4){0.f, 0.f, 0.f, 0.f};
    #pragma unroll
    for (int kc = 0; kc < 4; ++kc) {
      bf16x8 kf[4];
      #pragma unroll
      for (int n = 0; n < 4; ++n) {
        int r = n * 16 + fr;
        kf[n] = *(const bf16x8*)((const char*)&Kl[p][0] +
                 r * 256 + (((kc * 4 + g4) ^ (r & 7)) << 4));
      }
      #pragma unroll
      for (int n = 0; n < 4; ++n)
        #pragma unroll
        for (int m = 0; m < 2; ++m)
          sc[n][m] = mfma16x16x32(kf[n], aq[m][kc], sc[n][m]);
    }

    // ---- online softmax per m (mask only when local tile) ----
    #pragma unroll
    for (int m = 0; m < 2; ++m) {
      const int q = m * 16 + fr;
      float rmax = -1e30f;
      if (domask) {
        const int qrow = w * 32 + m * 16 + fr;      // row within tile
        #pragma unroll
        for (int n = 0; n < 4; ++n)
          #pragma unroll
          for (int j = 0; j < 4; ++j) {
            float lg = sc[n][m][j] * scale;
            int tok = (s & 1) * 64 + n * 16 + g4 * 4 + j;
            if (tok > qrow) lg = -1e10f;
            sc[n][m][j] = lg;
            rmax = fmaxf(rmax, lg);
          }
      } else {
        #pragma unroll
        for (int n = 0; n < 4; ++n)
          #pragma unroll
          for (int j = 0; j < 4; ++j) {
            float lg = sc[n][m][j] * scale;
            sc[n][m][j] = lg;
            rmax = fmaxf(rmax, lg);
          }
      }
      rmax = fmaxf(rmax, __shfl_xor(rmax, 16));
      rmax = fmaxf(rmax, __shfl_xor(rmax, 32));
      // defer-max (T13): rescale only if some row grew past threshold
      if (__any(rmax > mrun[m] + 8.f)) {
        float mnew = fmaxf(mrun[m], rmax);
        float alpha = __expf(mrun[m] - mnew);
        lrun[m] *= alpha;
        #pragma unroll
        for (int nd = 0; nd < 8; ++nd)
          #pragma unroll
          for (int j = 0; j < 4; ++j) o[m][nd][j] *= alpha;
        mrun[m] = mnew;
      }
      float rsum = 0.f;
      #pragma unroll
      for (int n = 0; n < 4; ++n) {
        bf16x4 pkv;
        #pragma unroll
        for (int j = 0; j < 4; ++j) {
          float pe = __expf(sc[n][m][j] - mrun[m]);
          rsum += pe;
          pkv[j] = (bf16_t)pe;
        }
        int off = q * 128 + ((((n << 1) | (g4 >> 1)) ^ (q & 7)) << 4) + ((g4 & 1) << 3);
        *(bf16x4*)(P + off) = pkv;
      }
      rsum += __shfl_xor(rsum, 16);
      rsum += __shfl_xor(rsum, 32);
      lrun[m] += rsum;
    }

    // ---- O^T += V^T P from Vl[p] + per-wave P ----
    #pragma unroll
    for (int kc2 = 0; kc2 < 2; ++kc2) {
      bf16x8 av[8];
      #pragma unroll
      for (int nd = 0; nd < 8; ++nd) {
        int r = nd * 16 + fr;
        av[nd] = *(const bf16x8*)((const char*)&Vl[p][0] +
                  r * 128 + (((kc2 * 4 + g4) ^ (r & 7)) << 4));
      }
      bf16x8 bp[2];
      #pragma unroll
      for (int m = 0; m < 2; ++m) {
        int q = m * 16 + fr;
        bp[m] = *(const bf16x8*)(P + q * 128 + ((((kc2 << 2) | g4) ^ (q & 7)) << 4));
      }
      #pragma unroll
      for (int nd = 0; nd < 8; ++nd)
        #pragma unroll
        for (int m = 0; m < 2; ++m)
          o[m][nd] = mfma16x16x32(av[nd], bp[m], o[m][nd]);
    }
    __syncthreads();   // next staging landed + all waves done with buf p
  }

  // ---- epilogue: normalize; per m: O^T -> LDS [16 q rows x 256B] -> store
  #pragma unroll
  for (int m = 0; m < 2; ++m) {
    float inv = 1.0f / lrun[m];
    #pragma unroll
    for (int nd = 0; nd < 8; ++nd) {
      bf16x4 pkv;
      #pragma unroll
      for (int j = 0; j < 4; ++j) pkv[j] = (bf16_t)(o[m][nd][j] * inv);
      int off = fr * 256 + ((((nd << 1) | (g4 >> 1)) ^ (fr & 7)) << 4) + ((g4 & 1) << 3);
      *(bf16x4*)(P + off) = pkv;
    }
    #pragma unroll
    for (int i = 0; i < 4; ++i) {
      int r = i * 4 + g4;
      int off = r * 256 + ((fr ^ (r & 7)) << 4);
      bf16x8 vrow = *(const bf16x8*)(P + off);
      size_t gaddr = (((size_t)b * 4096 + qt * 128 + w * 32 + m * 16 + r) * 2048)
                     + h * 128 + fr * 8;
      *(bf16x8*)(outB + gaddr) = vrow;
    }
  }
}

// ---------------------------------------------------------------------------
// workspace layout (bytes)
#define OFF_XB   ((size_t)0)            // x bf16            [8192][2048]  32MB
#define OFF_WQT  ((size_t)33554432)     // wq^T bf16         [2048][2048]   8MB
#define OFF_WKT  ((size_t)41943040)
#define OFF_WVT  ((size_t)50331648)
#define OFF_WOT  ((size_t)58720256)
#define OFF_QF   ((size_t)67108864)     // Q bf16 [B,H,S,D]  32MB
#define OFF_KF   ((size_t)100663296)    // K bf16 [B,H,S,D]  32MB
#define OFF_AT   ((size_t)134217728)    // attn out [B,S,2048] bf16 32MB
#define OFF_VT   ((size_t)167772160)    // V^T bf16 [B,H,D,S] 32MB

extern "C" void kernel_launch(void* const* d_in, const int* in_sizes, int n_in,
                              void* d_out, int out_size, void* d_ws, size_t ws_size,
                              hipStream_t stream) {
  (void)in_sizes; (void)n_in; (void)out_size; (void)ws_size;
  const float* x    = (const float*)d_in[0];
  const float* wq   = (const float*)d_in[1];
  const float* wk   = (const float*)d_in[2];
  const float* wv   = (const float*)d_in[3];
  const float* wo   = (const float*)d_in[4];
  const float* cosT = (const float*)d_in[5];
  const float* sinT = (const float*)d_in[6];
  const int*   anc  = (const int*)d_in[7];
  float* out = (float*)d_out;
  char* ws = (char*)d_ws;

  bf16_t* xb   = (bf16_t*)(ws + OFF_XB);
  bf16_t* wqt  = (bf16_t*)(ws + OFF_WQT);
  bf16_t* wkt  = (bf16_t*)(ws + OFF_WKT);
  bf16_t* wvt  = (bf16_t*)(ws + OFF_WVT);
  bf16_t* wot  = (bf16_t*)(ws + OFF_WOT);
  bf16_t* Qf   = (bf16_t*)(ws + OFF_QF);
  bf16_t* Kf   = (bf16_t*)(ws + OFF_KF);
  bf16_t* Vt   = (bf16_t*)(ws + OFF_VT);
  bf16_t* attnB = (bf16_t*)(ws + OFF_AT);

  cvt_f32_bf16<<<16384, 256, 0, stream>>>(x, xb);
  wtrans<<<dim3(32, 32), 256, 0, stream>>>(wq, wqt);
  wtrans<<<dim3(32, 32), 256, 0, stream>>>(wk, wkt);
  wtrans<<<dim3(32, 32), 256, 0, stream>>>(wv, wvt);
  wtrans<<<dim3(32, 32), 256, 0, stream>>>(wo, wot);
  gemm_bt<<<dim3(64, 16), 256, 0, stream>>>(xb, wqt, nullptr, Qf, 1);
  gemm_bt<<<dim3(64, 16), 256, 0, stream>>>(xb, wkt, nullptr, Kf, 1);
  gemm_bt<<<dim3(64, 16), 256, 0, stream>>>(xb, wvt, nullptr, Vt, 2);  // V^T direct
  rope_kernel<<<65536, 256, 0, stream>>>(Qf, Kf, cosT, sinT);
  attn_kernel<<<1024, 256, 0, stream>>>(Qf, Kf, Vt, anc, attnB);
  gemm_bt<<<dim3(64, 16), 256, 0, stream>>>(attnB, wot, out, nullptr, 0);
}

// Round 6
// 400.967 us; speedup vs baseline: 2.2919x; 1.1947x over previous
//
#include <hip/hip_runtime.h>
#include <hip/hip_bf16.h>

// ---------------------------------------------------------------------------
// KascadeReuseAttention: B=2,S=4096,H=16,D=128, TILE=128, T=32, TOPK=7(+local)
// R6: GEMMs -> 256x256 tile, 8-wave, 4-slot LDS ring (128KiB), counted
// vmcnt(4) + raw s_barrier pipeline (T2 swizzle + T3/T4 + T5 setprio).
// Attn/elementwise unchanged from R5.
// ---------------------------------------------------------------------------

typedef __bf16 bf16_t;
using bf16x8 = __attribute__((ext_vector_type(8))) __bf16;
using bf16x4 = __attribute__((ext_vector_type(4))) __bf16;
using f32x4  = __attribute__((ext_vector_type(4))) float;

typedef const __attribute__((address_space(1))) void* gas_ptr;
typedef __attribute__((address_space(3))) void* las_ptr;

__device__ __forceinline__ void async_copy16(const void* g, void* l) {
  __builtin_amdgcn_global_load_lds((gas_ptr)g, (las_ptr)l, 16, 0, 0);
}

__device__ __forceinline__ f32x4 mfma16x16x32(bf16x8 a, bf16x8 b, f32x4 c) {
  return __builtin_amdgcn_mfma_f32_16x16x32_bf16(a, b, c, 0, 0, 0);
}

// ---------------- elementwise f32 -> bf16 (vectorized) ----------------------
__global__ void cvt_f32_bf16(const float* __restrict__ X, bf16_t* __restrict__ Y) {
  int idx = blockIdx.x * 256 + threadIdx.x;
  float4 v = ((const float4*)X)[idx];
  bf16x4 r;
  r.x = (bf16_t)v.x; r.y = (bf16_t)v.y; r.z = (bf16_t)v.z; r.w = (bf16_t)v.w;
  ((bf16x4*)Y)[idx] = r;
}

// ---------------- weight transpose + convert: W[2048][2048] f32 -> Wt[n][k] bf16
__global__ void wtrans(const float* __restrict__ W, bf16_t* __restrict__ Wt) {
  __shared__ bf16_t t[64][66];
  const int r0 = blockIdx.x * 64, c0 = blockIdx.y * 64;
  const int tx = threadIdx.x & 63, ty = threadIdx.x >> 6;
  #pragma unroll
  for (int i = 0; i < 16; ++i) {
    int r = ty + 4 * i;
    t[r][tx] = (bf16_t)W[(size_t)(r0 + r) * 2048 + c0 + tx];
  }
  __syncthreads();
  #pragma unroll
  for (int i = 0; i < 16; ++i) {
    int n = ty + 4 * i;
    Wt[(size_t)(c0 + n) * 2048 + r0 + tx] = t[tx][n];
  }
}

// ---------------- GEMM 256x256: C[8192][2048] = A * Bt^T --------------------
// 8 waves (2Mx4N), per-wave 128x64 output. 64 phases of K=32.
// LDS: 4-slot ring, slot = phase&3, A[256][32]+B[256][32] bf16 per slot
// (4x(16+16)KB = 128KiB). Swizzle: 16B chunk cc ^= (row>>1)&3 -> 2-way (free)
// on both staging writes (source-preswizzled) and ds_read_b128 frag reads.
// Phase: {12 ds_read | STAGE(phase+2): 4 gload_lds | vmcnt(4) | raw barrier |
//         setprio(1) 32 MFMA setprio(0)}. vmcnt(0) only in the 2-phase tail.
// Ledger: slot p+2 last read at phase p-2 (>=2 barriers before overwrite);
// vmcnt(4)+barrier => slot p+1 fully landed (all threads) before p+1 reads.
// mode 0: f32 C row-major. mode 1: bf16 [B,H,S,D]. mode 2: bf16 V^T [B,H,D,S].
__global__ __launch_bounds__(512, 2) void gemm256(
    const bf16_t* __restrict__ A, const bf16_t* __restrict__ Bt,
    float* __restrict__ Cf, bf16_t* __restrict__ Cq, int mode)
{
  __shared__ bf16_t Apan[4][8192];
  __shared__ bf16_t Bpan[4][8192];
  const int bid = blockIdx.x;
  const int swz = (bid & 7) * 32 + (bid >> 3);    // XCD-chunked (256%8==0)
  const int bm = (swz >> 3) * 256, bn = (swz & 7) * 256;
  const int tid = threadIdx.x;
  const int w = tid >> 6, l = tid & 63;
  const int wr = w >> 2, wc = w & 3;
  const int fr = l & 15, g4 = l >> 4;

  // staging: thread owns chunks c0=tid, c1=tid+512 of each [256][32] panel
  const int c0 = tid, c1 = tid + 512;
  const int r0 = c0 >> 2, s0c = ((c0 & 3) ^ ((r0 >> 1) & 3)) * 8;
  const int r1 = c1 >> 2, s1c = ((c1 & 3) ^ ((r1 >> 1) & 3)) * 8;
  const bf16_t* aS0 = A  + (size_t)(bm + r0) * 2048 + s0c;
  const bf16_t* aS1 = A  + (size_t)(bm + r1) * 2048 + s1c;
  const bf16_t* bS0 = Bt + (size_t)(bn + r0) * 2048 + s0c;
  const bf16_t* bS1 = Bt + (size_t)(bn + r1) * 2048 + s1c;
  const int d0 = c0 * 16, d1 = c1 * 16;

  // frag-read byte offsets within a panel
  int aOff[8], bOff[4];
  #pragma unroll
  for (int m = 0; m < 8; ++m) {
    int R = wr * 128 + m * 16 + fr;
    aOff[m] = R * 64 + ((g4 ^ ((R >> 1) & 3)) << 4);
  }
  #pragma unroll
  for (int n = 0; n < 4; ++n) {
    int R = wc * 64 + n * 16 + fr;
    bOff[n] = R * 64 + ((g4 ^ ((R >> 1) & 3)) << 4);
  }

  f32x4 acc[8][4];
  #pragma unroll
  for (int m = 0; m < 8; ++m)
    #pragma unroll
    for (int n = 0; n < 4; ++n) acc[m][n] = (f32x4){0.f, 0.f, 0.f, 0.f};

  auto STAGE = [&](int phi2) {
    const int slot = phi2 & 3;
    const int kb = phi2 * 32;
    char* dA = (char*)&Apan[slot][0];
    char* dB = (char*)&Bpan[slot][0];
    async_copy16(aS0 + kb, dA + d0);
    async_copy16(aS1 + kb, dA + d1);
    async_copy16(bS0 + kb, dB + d0);
    async_copy16(bS1 + kb, dB + d1);
  };

  STAGE(0);
  STAGE(1);
  __syncthreads();   // prologue: full drain (once), slots 0,1 landed

  #pragma unroll 1
  for (int phi = 0; phi < 64; ++phi) {
    const int slot = phi & 3;
    const char* pa = (const char*)&Apan[slot][0];
    const char* pb = (const char*)&Bpan[slot][0];
    bf16x8 af[8], bfr[4];
    #pragma unroll
    for (int m = 0; m < 8; ++m) af[m] = *(const bf16x8*)(pa + aOff[m]);
    #pragma unroll
    for (int n = 0; n < 4; ++n) bfr[n] = *(const bf16x8*)(pb + bOff[n]);
    if (phi < 62) {
      STAGE(phi + 2);
      asm volatile("s_waitcnt vmcnt(4)" ::: "memory");   // slot phi+1 landed
    } else {
      asm volatile("s_waitcnt vmcnt(0)" ::: "memory");   // tail drain
    }
    __builtin_amdgcn_sched_barrier(0);
    __builtin_amdgcn_s_barrier();          // raw: no implicit vmcnt(0) drain
    __builtin_amdgcn_sched_barrier(0);
    __builtin_amdgcn_s_setprio(1);
    #pragma unroll
    for (int m = 0; m < 8; ++m)
      #pragma unroll
      for (int n = 0; n < 4; ++n)
        acc[m][n] = mfma16x16x32(af[m], bfr[n], acc[m][n]);
    __builtin_amdgcn_s_setprio(0);
    __builtin_amdgcn_sched_barrier(0);
  }

  if (mode == 2) {
    // V^T [BH*128 d][4096 s]: j-quad packs to one bf16x4 store
    #pragma unroll
    for (int m = 0; m < 8; ++m)
      #pragma unroll
      for (int n = 0; n < 4; ++n) {
        int colv = bn + wc * 64 + n * 16 + fr;
        int h_ = colv >> 7, d_ = colv & 127;
        int row0 = bm + wr * 128 + m * 16 + g4 * 4;
        int b_ = row0 >> 12, sr = row0 & 4095;
        bf16x4 pk;
        #pragma unroll
        for (int j = 0; j < 4; ++j) pk[j] = (bf16_t)acc[m][n][j];
        *(bf16x4*)&Cq[(((size_t)(b_ * 16 + h_)) * 128 + d_) * 4096 + sr] = pk;
      }
    return;
  }

  #pragma unroll
  for (int m = 0; m < 8; ++m)
    #pragma unroll
    for (int n = 0; n < 4; ++n)
      #pragma unroll
      for (int j = 0; j < 4; ++j) {
        int row = bm + wr * 128 + m * 16 + g4 * 4 + j;
        int col = bn + wc * 64 + n * 16 + fr;
        if (mode == 0) {
          Cf[(size_t)row * 2048 + col] = acc[m][n][j];
        } else {
          int b = row >> 12, s = row & 4095, h = col >> 7, d = col & 127;
          Cq[(((size_t)(b * 16 + h)) * 4096 + s) * 128 + d] = (bf16_t)acc[m][n][j];
        }
      }
}

// ---------------- RoPE in place on Q,K [BH=32][S=4096][D=128] bf16 ----------
__global__ void rope_kernel(bf16_t* __restrict__ Q, bf16_t* __restrict__ K,
                            const float* __restrict__ cosT, const float* __restrict__ sinT)
{
  int gid = blockIdx.x * 4 + (threadIdx.x >> 6);
  int i = threadIdx.x & 63;
  bf16_t* p = ((gid < 131072) ? Q : K) + (size_t)(gid & 131071) * 128;
  int s = gid & 4095;
  float c = cosT[s * 64 + i], sn = sinT[s * 64 + i];
  float x0 = (float)p[i], x1 = (float)p[i + 64];
  p[i]      = (bf16_t)(x0 * c - x1 * sn);
  p[i + 64] = (bf16_t)(x1 * c + x0 * sn);
}

// ---------------- sparse flash attention (LDS-shared, pipelined, skip) ------
__global__ __launch_bounds__(256, 2) void attn_kernel(
    const bf16_t* __restrict__ Qf, const bf16_t* __restrict__ Kf,
    const bf16_t* __restrict__ Vt, const int* __restrict__ anchors,
    bf16_t* __restrict__ outB)   // [B,S,2048] bf16
{
  __shared__ bf16_t Kl[2][8192];    // [64 tok][128 d] swizzled, 16KB each
  __shared__ bf16_t Vl[2][8192];    // [128 d][64 tok] swizzled, 16KB each
  __shared__ bf16_t Pbuf[4][2048];  // per-wave 4KB    (total LDS = 80KB exact)
  const int orig = blockIdx.x;
  const int blk = (orig & 7) * 128 + (orig >> 3);   // XCD-chunked swizzle
  const int qt = 31 - (blk & 31);                   // high-qt (long) blocks first
  const int h = (blk >> 5) & 15, b = blk >> 9;
  const int bh = b * 16 + h;
  const int tid = threadIdx.x, w = tid >> 6, l = tid & 63;
  const int fr = l & 15, g4 = l >> 4;
  const float scale = 0.08838834764831845f;   // 1/sqrt(128)

  // ---- build packed active-tile list (identical in every thread) ----
  const int* anc = anchors + ((size_t)bh * 32 + qt) * 7;
  unsigned long long pk = 0;
  int nt = 0;
  #pragma unroll
  for (int t = 0; t < 7; ++t) {
    int v = anc[t];
    if (v <= qt) { pk |= (unsigned long long)v << (5 * nt); ++nt; }
  }
  pk |= (unsigned long long)qt << (5 * nt); ++nt;   // local tile last
  const int NS = nt * 2;

  const bf16_t* Qbase = Qf + (size_t)bh * 4096 * 128;
  const bf16_t* Kbase = Kf + (size_t)bh * 4096 * 128;
  const bf16_t* Vbase = Vt + (size_t)bh * 128 * 4096;
  char* P = (char*)&Pbuf[w][0];

  auto STAGE = [&](int tb2, int p) {
    const bf16_t* ksrc = Kbase + (size_t)tb2 * 128;
    const bf16_t* vsrc = Vbase + tb2;
    char* kd = (char*)&Kl[p][0];
    char* vd = (char*)&Vl[p][0];
    #pragma unroll
    for (int i = 0; i < 4; ++i) {
      int c = tid + i * 256;                 // 0..1023
      int kr = c >> 4, kcol = c & 15;        // K: 64 rows x 16 chunks
      async_copy16(ksrc + (size_t)kr * 128 + (size_t)((kcol ^ (kr & 7)) * 8),
                   kd + c * 16);
      int vr = c >> 3, vcol = c & 7;         // V^T: 128 rows x 8 chunks
      async_copy16(vsrc + (size_t)vr * 4096 + (size_t)((vcol ^ (vr & 7)) * 8),
                   vd + c * 16);
    }
  };

  // Q fragments (B-operand: col = q-row, k-chunk g4*8), direct from global
  bf16x8 aq[2][4];
  #pragma unroll
  for (int m = 0; m < 2; ++m) {
    int q = qt * 128 + w * 32 + m * 16 + fr;
    #pragma unroll
    for (int kc = 0; kc < 4; ++kc)
      aq[m][kc] = *(const bf16x8*)(Qbase + (size_t)q * 128 + kc * 32 + g4 * 8);
  }

  STAGE((int)(pk & 31) * 128, 0);
  __syncthreads();   // step-0 buffers landed

  float mrun[2] = {-1e30f, -1e30f};
  float lrun[2] = {0.f, 0.f};
  f32x4 o[2][8];
  #pragma unroll
  for (int m = 0; m < 2; ++m)
    #pragma unroll
    for (int nd = 0; nd < 8; ++nd) o[m][nd] = (f32x4){0.f, 0.f, 0.f, 0.f};

  for (int s = 0; s < NS; ++s) {
    const int p = s & 1;
    const int ts = (int)((pk >> (5 * (s >> 1))) & 31);
    const bool domask = (ts == qt);
    if (s + 1 < NS) {
      int s1 = s + 1;
      int ts1 = (int)((pk >> (5 * (s1 >> 1))) & 31);
      STAGE(ts1 * 128 + (s1 & 1) * 64, p ^ 1);
    }

    // ---- S^T = K Q^T from Kl[p] ----
    f32x4 sc[4][2];
    #pragma unroll
    for (int n = 0; n < 4; ++n)
      #pragma unroll
      for (int m = 0; m < 2; ++m) sc[n][m] = (f32x4){0.f, 0.f, 0.f, 0.f};
    #pragma unroll
    for (int kc = 0; kc < 4; ++kc) {
      bf16x8 kf[4];
      #pragma unroll
      for (int n = 0; n < 4; ++n) {
        int r = n * 16 + fr;
        kf[n] = *(const bf16x8*)((const char*)&Kl[p][0] +
                 r * 256 + (((kc * 4 + g4) ^ (r & 7)) << 4));
      }
      #pragma unroll
      for (int n = 0; n < 4; ++n)
        #pragma unroll
        for (int m = 0; m < 2; ++m)
          sc[n][m] = mfma16x16x32(kf[n], aq[m][kc], sc[n][m]);
    }

    // ---- online softmax per m (mask only when local tile) ----
    #pragma unroll
    for (int m = 0; m < 2; ++m) {
      const int q = m * 16 + fr;
      float rmax = -1e30f;
      if (domask) {
        const int qrow = w * 32 + m * 16 + fr;
        #pragma unroll
        for (int n = 0; n < 4; ++n)
          #pragma unroll
          for (int j = 0; j < 4; ++j) {
            float lg = sc[n][m][j] * scale;
            int tok = (s & 1) * 64 + n * 16 + g4 * 4 + j;
            if (tok > qrow) lg = -1e10f;
            sc[n][m][j] = lg;
            rmax = fmaxf(rmax, lg);
          }
      } else {
        #pragma unroll
        for (int n = 0; n < 4; ++n)
          #pragma unroll
          for (int j = 0; j < 4; ++j) {
            float lg = sc[n][m][j] * scale;
            sc[n][m][j] = lg;
            rmax = fmaxf(rmax, lg);
          }
      }
      rmax = fmaxf(rmax, __shfl_xor(rmax, 16));
      rmax = fmaxf(rmax, __shfl_xor(rmax, 32));
      if (__any(rmax > mrun[m] + 8.f)) {      // defer-max (T13)
        float mnew = fmaxf(mrun[m], rmax);
        float alpha = __expf(mrun[m] - mnew);
        lrun[m] *= alpha;
        #pragma unroll
        for (int nd = 0; nd < 8; ++nd)
          #pragma unroll
          for (int j = 0; j < 4; ++j) o[m][nd][j] *= alpha;
        mrun[m] = mnew;
      }
      float rsum = 0.f;
      #pragma unroll
      for (int n = 0; n < 4; ++n) {
        bf16x4 pkv;
        #pragma unroll
        for (int j = 0; j < 4; ++j) {
          float pe = __expf(sc[n][m][j] - mrun[m]);
          rsum += pe;
          pkv[j] = (bf16_t)pe;
        }
        int off = q * 128 + ((((n << 1) | (g4 >> 1)) ^ (q & 7)) << 4) + ((g4 & 1) << 3);
        *(bf16x4*)(P + off) = pkv;
      }
      rsum += __shfl_xor(rsum, 16);
      rsum += __shfl_xor(rsum, 32);
      lrun[m] += rsum;
    }

    // ---- O^T += V^T P ----
    #pragma unroll
    for (int kc2 = 0; kc2 < 2; ++kc2) {
      bf16x8 av[8];
      #pragma unroll
      for (int nd = 0; nd < 8; ++nd) {
        int r = nd * 16 + fr;
        av[nd] = *(const bf16x8*)((const char*)&Vl[p][0] +
                  r * 128 + (((kc2 * 4 + g4) ^ (r & 7)) << 4));
      }
      bf16x8 bp[2];
      #pragma unroll
      for (int m = 0; m < 2; ++m) {
        int q = m * 16 + fr;
        bp[m] = *(const bf16x8*)(P + q * 128 + ((((kc2 << 2) | g4) ^ (q & 7)) << 4));
      }
      #pragma unroll
      for (int nd = 0; nd < 8; ++nd)
        #pragma unroll
        for (int m = 0; m < 2; ++m)
          o[m][nd] = mfma16x16x32(av[nd], bp[m], o[m][nd]);
    }
    __syncthreads();
  }

  // ---- epilogue ----
  #pragma unroll
  for (int m = 0; m < 2; ++m) {
    float inv = 1.0f / lrun[m];
    #pragma unroll
    for (int nd = 0; nd < 8; ++nd) {
      bf16x4 pkv;
      #pragma unroll
      for (int j = 0; j < 4; ++j) pkv[j] = (bf16_t)(o[m][nd][j] * inv);
      int off = fr * 256 + ((((nd << 1) | (g4 >> 1)) ^ (fr & 7)) << 4) + ((g4 & 1) << 3);
      *(bf16x4*)(P + off) = pkv;
    }
    #pragma unroll
    for (int i = 0; i < 4; ++i) {
      int r = i * 4 + g4;
      int off = r * 256 + ((fr ^ (r & 7)) << 4);
      bf16x8 vrow = *(const bf16x8*)(P + off);
      size_t gaddr = (((size_t)b * 4096 + qt * 128 + w * 32 + m * 16 + r) * 2048)
                     + h * 128 + fr * 8;
      *(bf16x8*)(outB + gaddr) = vrow;
    }
  }
}

// ---------------------------------------------------------------------------
// workspace layout (bytes)
#define OFF_XB   ((size_t)0)            // x bf16            [8192][2048]  32MB
#define OFF_WQT  ((size_t)33554432)     // wq^T bf16         [2048][2048]   8MB
#define OFF_WKT  ((size_t)41943040)
#define OFF_WVT  ((size_t)50331648)
#define OFF_WOT  ((size_t)58720256)
#define OFF_QF   ((size_t)67108864)     // Q bf16 [B,H,S,D]  32MB
#define OFF_KF   ((size_t)100663296)    // K bf16 [B,H,S,D]  32MB
#define OFF_AT   ((size_t)134217728)    // attn out [B,S,2048] bf16 32MB
#define OFF_VT   ((size_t)167772160)    // V^T bf16 [B,H,D,S] 32MB

extern "C" void kernel_launch(void* const* d_in, const int* in_sizes, int n_in,
                              void* d_out, int out_size, void* d_ws, size_t ws_size,
                              hipStream_t stream) {
  (void)in_sizes; (void)n_in; (void)out_size; (void)ws_size;
  const float* x    = (const float*)d_in[0];
  const float* wq   = (const float*)d_in[1];
  const float* wk   = (const float*)d_in[2];
  const float* wv   = (const float*)d_in[3];
  const float* wo   = (const float*)d_in[4];
  const float* cosT = (const float*)d_in[5];
  const float* sinT = (const float*)d_in[6];
  const int*   anc  = (const int*)d_in[7];
  float* out = (float*)d_out;
  char* ws = (char*)d_ws;

  bf16_t* xb   = (bf16_t*)(ws + OFF_XB);
  bf16_t* wqt  = (bf16_t*)(ws + OFF_WQT);
  bf16_t* wkt  = (bf16_t*)(ws + OFF_WKT);
  bf16_t* wvt  = (bf16_t*)(ws + OFF_WVT);
  bf16_t* wot  = (bf16_t*)(ws + OFF_WOT);
  bf16_t* Qf   = (bf16_t*)(ws + OFF_QF);
  bf16_t* Kf   = (bf16_t*)(ws + OFF_KF);
  bf16_t* Vt   = (bf16_t*)(ws + OFF_VT);
  bf16_t* attnB = (bf16_t*)(ws + OFF_AT);

  cvt_f32_bf16<<<16384, 256, 0, stream>>>(x, xb);
  wtrans<<<dim3(32, 32), 256, 0, stream>>>(wq, wqt);
  wtrans<<<dim3(32, 32), 256, 0, stream>>>(wk, wkt);
  wtrans<<<dim3(32, 32), 256, 0, stream>>>(wv, wvt);
  wtrans<<<dim3(32, 32), 256, 0, stream>>>(wo, wot);
  gemm256<<<256, 512, 0, stream>>>(xb, wqt, nullptr, Qf, 1);
  gemm256<<<256, 512, 0, stream>>>(xb, wkt, nullptr, Kf, 1);
  gemm256<<<256, 512, 0, stream>>>(xb, wvt, nullptr, Vt, 2);   // V^T direct
  rope_kernel<<<65536, 256, 0, stream>>>(Qf, Kf, cosT, sinT);
  attn_kernel<<<1024, 256, 0, stream>>>(Qf, Kf, Vt, anc, attnB);
  gemm256<<<256, 512, 0, stream>>>(attnB, wot, out, nullptr, 0);
}

// Round 7
// 382.442 us; speedup vs baseline: 2.4029x; 1.0484x over previous
//
#include <hip/hip_runtime.h>
#include <hip/hip_bf16.h>

// ---------------------------------------------------------------------------
// KascadeReuseAttention: B=2,S=4096,H=16,D=128, TILE=128, T=32, TOPK=7(+local)
// R7: (1) QKV fused into ONE 256x256 pipelined GEMM over Bt=concat[6144][2048]
//     with RoPE fused into the f32 epilogue (4Mx2N wave tiling puts the
//     (d,d+64) pair in-thread) and V^T written directly; rope kernel deleted.
//     (2) attn: 8 waves x 16 q-rows (512 thr) -> 4 waves/SIMD at same 80KB LDS.
// ---------------------------------------------------------------------------

typedef __bf16 bf16_t;
using bf16x8 = __attribute__((ext_vector_type(8))) __bf16;
using bf16x4 = __attribute__((ext_vector_type(4))) __bf16;
using f32x4  = __attribute__((ext_vector_type(4))) float;

typedef const __attribute__((address_space(1))) void* gas_ptr;
typedef __attribute__((address_space(3))) void* las_ptr;

__device__ __forceinline__ void async_copy16(const void* g, void* l) {
  __builtin_amdgcn_global_load_lds((gas_ptr)g, (las_ptr)l, 16, 0, 0);
}

__device__ __forceinline__ f32x4 mfma16x16x32(bf16x8 a, bf16x8 b, f32x4 c) {
  return __builtin_amdgcn_mfma_f32_16x16x32_bf16(a, b, c, 0, 0, 0);
}

// ---------------- elementwise f32 -> bf16 (vectorized) ----------------------
__global__ void cvt_f32_bf16(const float* __restrict__ X, bf16_t* __restrict__ Y) {
  int idx = blockIdx.x * 256 + threadIdx.x;
  float4 v = ((const float4*)X)[idx];
  bf16x4 r;
  r.x = (bf16_t)v.x; r.y = (bf16_t)v.y; r.z = (bf16_t)v.z; r.w = (bf16_t)v.w;
  ((bf16x4*)Y)[idx] = r;
}

// ---------------- weight transpose + convert: W[2048][2048] f32 -> Wt[n][k] bf16
__global__ void wtrans(const float* __restrict__ W, bf16_t* __restrict__ Wt) {
  __shared__ bf16_t t[64][66];
  const int r0 = blockIdx.x * 64, c0 = blockIdx.y * 64;
  const int tx = threadIdx.x & 63, ty = threadIdx.x >> 6;
  #pragma unroll
  for (int i = 0; i < 16; ++i) {
    int r = ty + 4 * i;
    t[r][tx] = (bf16_t)W[(size_t)(r0 + r) * 2048 + c0 + tx];
  }
  __syncthreads();
  #pragma unroll
  for (int i = 0; i < 16; ++i) {
    int n = ty + 4 * i;
    Wt[(size_t)(c0 + n) * 2048 + r0 + tx] = t[tx][n];
  }
}

// ---------------- GEMM 256x256 pipelined: C[8192][Ntot] = A * Bt^T ----------
// 8 waves as 4M x 2N: per-wave 64Mx128N (full head span in-thread for rope).
// LDS: 4-slot ring (A+B [256][32] panels, 128KiB). Phase: {12 ds_read |
// STAGE(p+2) 4 gload_lds | vmcnt(4) | raw barrier | setprio 32 MFMA}.
// Ledger (unchanged from R6): slot p+2 last read 2 barriers earlier; vmcnt(4)
// at phase p confirms slot p+1 landed.
// mode 0: f32 C row-major [8192][2048] (nb=8).
// mode 1: fused QKV (nb=24): proj=col>>11 -> Q,K rope'd bf16 [B,H,S,D];
//         V -> V^T bf16 [B,H,D,S].
__global__ __launch_bounds__(512, 2) void gemm256(
    const bf16_t* __restrict__ A, const bf16_t* __restrict__ Bt,
    int nb, int mode, float* __restrict__ Cf,
    bf16_t* __restrict__ outQ, bf16_t* __restrict__ outK,
    bf16_t* __restrict__ outVT,
    const float* __restrict__ cosT, const float* __restrict__ sinT)
{
  __shared__ bf16_t Apan[4][8192];
  __shared__ bf16_t Bpan[4][8192];
  const int bid = blockIdx.x;
  const int cpx = gridDim.x >> 3;
  const int swz = (bid & 7) * cpx + (bid >> 3);   // XCD-chunked (grid%8==0)
  const int bm = (swz / nb) * 256, bn = (swz % nb) * 256;
  const int tid = threadIdx.x;
  const int w = tid >> 6, l = tid & 63;
  const int wr = w >> 1, wc = w & 1;              // 4M x 2N
  const int fr = l & 15, g4 = l >> 4;

  // staging: thread owns chunks c0=tid, c1=tid+512 of each [256][32] panel
  const int c0 = tid, c1 = tid + 512;
  const int r0 = c0 >> 2, s0c = ((c0 & 3) ^ ((r0 >> 1) & 3)) * 8;
  const int r1 = c1 >> 2, s1c = ((c1 & 3) ^ ((r1 >> 1) & 3)) * 8;
  const bf16_t* aS0 = A  + (size_t)(bm + r0) * 2048 + s0c;
  const bf16_t* aS1 = A  + (size_t)(bm + r1) * 2048 + s1c;
  const bf16_t* bS0 = Bt + (size_t)(bn + r0) * 2048 + s0c;
  const bf16_t* bS1 = Bt + (size_t)(bn + r1) * 2048 + s1c;
  const int d0 = c0 * 16, d1 = c1 * 16;

  // frag-read byte offsets within a panel
  int aOff[4], bOff[8];
  #pragma unroll
  for (int m = 0; m < 4; ++m) {
    int R = wr * 64 + m * 16 + fr;
    aOff[m] = R * 64 + ((g4 ^ ((R >> 1) & 3)) << 4);
  }
  #pragma unroll
  for (int n = 0; n < 8; ++n) {
    int R = wc * 128 + n * 16 + fr;
    bOff[n] = R * 64 + ((g4 ^ ((R >> 1) & 3)) << 4);
  }

  f32x4 acc[4][8];
  #pragma unroll
  for (int m = 0; m < 4; ++m)
    #pragma unroll
    for (int n = 0; n < 8; ++n) acc[m][n] = (f32x4){0.f, 0.f, 0.f, 0.f};

  auto STAGE = [&](int phi2) {
    const int slot = phi2 & 3;
    const int kb = phi2 * 32;
    char* dA = (char*)&Apan[slot][0];
    char* dB = (char*)&Bpan[slot][0];
    async_copy16(aS0 + kb, dA + d0);
    async_copy16(aS1 + kb, dA + d1);
    async_copy16(bS0 + kb, dB + d0);
    async_copy16(bS1 + kb, dB + d1);
  };

  STAGE(0);
  STAGE(1);
  __syncthreads();   // prologue: full drain (once), slots 0,1 landed

  #pragma unroll 1
  for (int phi = 0; phi < 64; ++phi) {
    const int slot = phi & 3;
    const char* pa = (const char*)&Apan[slot][0];
    const char* pb = (const char*)&Bpan[slot][0];
    bf16x8 af[4], bfr[8];
    #pragma unroll
    for (int m = 0; m < 4; ++m) af[m] = *(const bf16x8*)(pa + aOff[m]);
    #pragma unroll
    for (int n = 0; n < 8; ++n) bfr[n] = *(const bf16x8*)(pb + bOff[n]);
    if (phi < 62) {
      STAGE(phi + 2);
      asm volatile("s_waitcnt vmcnt(4)" ::: "memory");   // slot phi+1 landed
    } else {
      asm volatile("s_waitcnt vmcnt(0)" ::: "memory");   // tail drain
    }
    __builtin_amdgcn_sched_barrier(0);
    __builtin_amdgcn_s_barrier();          // raw: no implicit vmcnt(0) drain
    __builtin_amdgcn_sched_barrier(0);
    __builtin_amdgcn_s_setprio(1);
    #pragma unroll
    for (int m = 0; m < 4; ++m)
      #pragma unroll
      for (int n = 0; n < 8; ++n)
        acc[m][n] = mfma16x16x32(af[m], bfr[n], acc[m][n]);
    __builtin_amdgcn_s_setprio(0);
    __builtin_amdgcn_sched_barrier(0);
  }

  if (mode == 0) {
    #pragma unroll
    for (int m = 0; m < 4; ++m)
      #pragma unroll
      for (int n = 0; n < 8; ++n)
        #pragma unroll
        for (int j = 0; j < 4; ++j) {
          int row = bm + wr * 64 + m * 16 + g4 * 4 + j;
          int col = bn + wc * 128 + n * 16 + fr;
          Cf[(size_t)row * 2048 + col] = acc[m][n][j];
        }
    return;
  }

  // ---- fused QKV epilogue ----
  const int colbase = bn + wc * 128;          // wave-uniform, multiple of 128
  const int proj = colbase >> 11;             // 0=Q 1=K 2=V
  const int hh = (colbase & 2047) >> 7;
  if (proj == 2) {
    // V^T [BH*128 d][4096 s]: j-quad packs to one bf16x4 store
    #pragma unroll
    for (int m = 0; m < 4; ++m) {
      int row0 = bm + wr * 64 + m * 16 + g4 * 4;
      int b_ = row0 >> 12, sr = row0 & 4095;
      #pragma unroll
      for (int n = 0; n < 8; ++n) {
        int d_ = n * 16 + fr;
        bf16x4 pkv;
        #pragma unroll
        for (int j = 0; j < 4; ++j) pkv[j] = (bf16_t)acc[m][n][j];
        *(bf16x4*)&outVT[(((size_t)(b_ * 16 + hh)) * 128 + d_) * 4096 + sr] = pkv;
      }
    }
  } else {
    bf16_t* dst = proj ? outK : outQ;
    #pragma unroll
    for (int m = 0; m < 4; ++m) {
      int row0 = bm + wr * 64 + m * 16 + g4 * 4;
      int b_ = row0 >> 12, s0 = row0 & 4095;
      size_t hbase = ((size_t)(b_ * 16 + hh)) * 4096;
      #pragma unroll
      for (int n = 0; n < 4; ++n) {
        int d = n * 16 + fr;
        #pragma unroll
        for (int j = 0; j < 4; ++j) {
          int s = s0 + j;
          float c  = cosT[s * 64 + d];
          float sn = sinT[s * 64 + d];
          float x0 = acc[m][n][j], x1 = acc[m][n + 4][j];
          dst[(hbase + s) * 128 + d]      = (bf16_t)(x0 * c - x1 * sn);
          dst[(hbase + s) * 128 + d + 64] = (bf16_t)(x1 * c + x0 * sn);
        }
      }
    }
  }
}

// ---------------- sparse flash attention (8 waves x 16 q-rows) --------------
// block = (b,h,qt): 512 threads, wave owns 16 q-rows -> 4 waves/SIMD at
// 2 blocks/CU (LDS exactly 80KB). Active tiles only (tsel<=qt), packed 5-bit
// reg list. KVBLK=64 double-buffered via gload_lds (source-preswizzled
// chunk^=row&7); stage s+1 before compute s; 1 barrier/step. Mask only local
// tile; defer-max (T13). Swapped QK^T / PV; P packed bf16x4 per-wave LDS.
__global__ __launch_bounds__(512, 4) void attn_kernel(
    const bf16_t* __restrict__ Qf, const bf16_t* __restrict__ Kf,
    const bf16_t* __restrict__ Vt, const int* __restrict__ anchors,
    bf16_t* __restrict__ outB)   // [B,S,2048] bf16
{
  __shared__ bf16_t Kl[2][8192];    // [64 tok][128 d] swizzled, 16KB each
  __shared__ bf16_t Vl[2][8192];    // [128 d][64 tok] swizzled, 16KB each
  __shared__ bf16_t Pbuf[8][1024];  // per-wave 2KB  (total LDS = 80KB exact)
  const int orig = blockIdx.x;
  const int blk = (orig & 7) * 128 + (orig >> 3);   // XCD-chunked swizzle
  const int qt = 31 - (blk & 31);                   // high-qt (long) blocks first
  const int h = (blk >> 5) & 15, b = blk >> 9;
  const int bh = b * 16 + h;
  const int tid = threadIdx.x, w = tid >> 6, l = tid & 63;
  const int fr = l & 15, g4 = l >> 4;
  const float scale = 0.08838834764831845f;   // 1/sqrt(128)

  // ---- packed active-tile list (identical in every thread) ----
  const int* anc = anchors + ((size_t)bh * 32 + qt) * 7;
  unsigned long long pk = 0;
  int nt = 0;
  #pragma unroll
  for (int t = 0; t < 7; ++t) {
    int v = anc[t];
    if (v <= qt) { pk |= (unsigned long long)v << (5 * nt); ++nt; }
  }
  pk |= (unsigned long long)qt << (5 * nt); ++nt;   // local tile last
  const int NS = nt * 2;

  const bf16_t* Qbase = Qf + (size_t)bh * 4096 * 128;
  const bf16_t* Kbase = Kf + (size_t)bh * 4096 * 128;
  const bf16_t* Vbase = Vt + (size_t)bh * 128 * 4096;
  char* P = (char*)&Pbuf[w][0];

  auto STAGE = [&](int tb2, int p) {
    const bf16_t* ksrc = Kbase + (size_t)tb2 * 128;
    const bf16_t* vsrc = Vbase + tb2;
    char* kd = (char*)&Kl[p][0];
    char* vd = (char*)&Vl[p][0];
    #pragma unroll
    for (int i = 0; i < 2; ++i) {
      int c = tid + i * 512;                 // 0..1023
      int kr = c >> 4, kcol = c & 15;        // K: 64 rows x 16 chunks
      async_copy16(ksrc + (size_t)kr * 128 + (size_t)((kcol ^ (kr & 7)) * 8),
                   kd + c * 16);
      int vr = c >> 3, vcol = c & 7;         // V^T: 128 rows x 8 chunks
      async_copy16(vsrc + (size_t)vr * 4096 + (size_t)((vcol ^ (vr & 7)) * 8),
                   vd + c * 16);
    }
  };

  // Q fragments (B-operand: col = q-row, k-chunk g4*8), direct from global
  const int qrow = qt * 128 + w * 16 + fr;
  bf16x8 aq[4];
  #pragma unroll
  for (int kc = 0; kc < 4; ++kc)
    aq[kc] = *(const bf16x8*)(Qbase + (size_t)qrow * 128 + kc * 32 + g4 * 8);

  STAGE((int)(pk & 31) * 128, 0);
  __syncthreads();   // step-0 buffers landed

  float mrun = -1e30f, lrun = 0.f;
  f32x4 o[8];
  #pragma unroll
  for (int nd = 0; nd < 8; ++nd) o[nd] = (f32x4){0.f, 0.f, 0.f, 0.f};

  for (int s = 0; s < NS; ++s) {
    const int p = s & 1;
    const int ts = (int)((pk >> (5 * (s >> 1))) & 31);
    const bool domask = (ts == qt);
    if (s + 1 < NS) {
      int s1 = s + 1;
      int ts1 = (int)((pk >> (5 * (s1 >> 1))) & 31);
      STAGE(ts1 * 128 + (s1 & 1) * 64, p ^ 1);
    }

    // ---- S^T = K Q^T from Kl[p]: sc[n], rows=tok(g4*4+j), cols=q(fr) ----
    f32x4 sc[4];
    #pragma unroll
    for (int n = 0; n < 4; ++n) sc[n] = (f32x4){0.f, 0.f, 0.f, 0.f};
    #pragma unroll
    for (int kc = 0; kc < 4; ++kc) {
      bf16x8 kf[4];
      #pragma unroll
      for (int n = 0; n < 4; ++n) {
        int r = n * 16 + fr;
        kf[n] = *(const bf16x8*)((const char*)&Kl[p][0] +
                 r * 256 + (((kc * 4 + g4) ^ (r & 7)) << 4));
      }
      #pragma unroll
      for (int n = 0; n < 4; ++n)
        sc[n] = mfma16x16x32(kf[n], aq[kc], sc[n]);
    }

    // ---- mask (local tile only) + online softmax ----
    float rmax = -1e30f;
    if (domask) {
      const int qr = w * 16 + fr;            // row within tile
      #pragma unroll
      for (int n = 0; n < 4; ++n)
        #pragma unroll
        for (int j = 0; j < 4; ++j) {
          float lg = sc[n][j] * scale;
          int tok = (s & 1) * 64 + n * 16 + g4 * 4 + j;
          if (tok > qr) lg = -1e10f;
          sc[n][j] = lg;
          rmax = fmaxf(rmax, lg);
        }
    } else {
      #pragma unroll
      for (int n = 0; n < 4; ++n)
        #pragma unroll
        for (int j = 0; j < 4; ++j) {
          float lg = sc[n][j] * scale;
          sc[n][j] = lg;
          rmax = fmaxf(rmax, lg);
        }
    }
    rmax = fmaxf(rmax, __shfl_xor(rmax, 16));
    rmax = fmaxf(rmax, __shfl_xor(rmax, 32));
    if (__any(rmax > mrun + 8.f)) {          // defer-max (T13)
      float mnew = fmaxf(mrun, rmax);
      float alpha = __expf(mrun - mnew);
      lrun *= alpha;
      #pragma unroll
      for (int nd = 0; nd < 8; ++nd)
        #pragma unroll
        for (int j = 0; j < 4; ++j) o[nd][j] *= alpha;
      mrun = mnew;
    }
    float rsum = 0.f;
    #pragma unroll
    for (int n = 0; n < 4; ++n) {
      bf16x4 pkv;
      #pragma unroll
      for (int j = 0; j < 4; ++j) {
        float pe = __expf(sc[n][j] - mrun);
        rsum += pe;
        pkv[j] = (bf16_t)pe;
      }
      int off = fr * 128 + ((((n << 1) | (g4 >> 1)) ^ (fr & 7)) << 4) + ((g4 & 1) << 3);
      *(bf16x4*)(P + off) = pkv;
    }
    rsum += __shfl_xor(rsum, 16);
    rsum += __shfl_xor(rsum, 32);
    lrun += rsum;

    // ---- O^T += V^T P from Vl[p] + per-wave P ----
    #pragma unroll
    for (int kc2 = 0; kc2 < 2; ++kc2) {
      bf16x8 av[8];
      #pragma unroll
      for (int nd = 0; nd < 8; ++nd) {
        int r = nd * 16 + fr;
        av[nd] = *(const bf16x8*)((const char*)&Vl[p][0] +
                  r * 128 + (((kc2 * 4 + g4) ^ (r & 7)) << 4));
      }
      bf16x8 bp = *(const bf16x8*)(P + fr * 128 + ((((kc2 << 2) | g4) ^ (fr & 7)) << 4));
      #pragma unroll
      for (int nd = 0; nd < 8; ++nd)
        o[nd] = mfma16x16x32(av[nd], bp, o[nd]);
    }
    __syncthreads();   // next staging landed + all waves done with buf p
  }

  // ---- epilogue: normalize; O^T -> per-wave scratch (Kl dead) -> store ----
  {
    char* E = (char*)&Kl[0][0] + w * 4096;   // 16 rows x 256B per wave
    float inv = 1.0f / lrun;
    #pragma unroll
    for (int nd = 0; nd < 8; ++nd) {
      bf16x4 pkv;
      #pragma unroll
      for (int j = 0; j < 4; ++j) pkv[j] = (bf16_t)(o[nd][j] * inv);
      int off = fr * 256 + ((((nd << 1) | (g4 >> 1)) ^ (fr & 7)) << 4) + ((g4 & 1) << 3);
      *(bf16x4*)(E + off) = pkv;
    }
    #pragma unroll
    for (int i = 0; i < 4; ++i) {
      int r = i * 4 + g4;
      int off = r * 256 + ((fr ^ (r & 7)) << 4);
      bf16x8 vrow = *(const bf16x8*)(E + off);
      size_t gaddr = (((size_t)b * 4096 + qt * 128 + w * 16 + r) * 2048)
                     + h * 128 + fr * 8;
      *(bf16x8*)(outB + gaddr) = vrow;
    }
  }
}

// ---------------------------------------------------------------------------
// workspace layout (bytes)
#define OFF_XB   ((size_t)0)            // x bf16            [8192][2048]  32MB
#define OFF_WCAT ((size_t)33554432)     // concat wq^T|wk^T|wv^T bf16 [6144][2048] 24MB
#define OFF_WOT  ((size_t)58720256)     // wo^T bf16 [2048][2048] 8MB
#define OFF_QF   ((size_t)67108864)     // Q bf16 [B,H,S,D]  32MB
#define OFF_KF   ((size_t)100663296)    // K bf16 [B,H,S,D]  32MB
#define OFF_AT   ((size_t)134217728)    // attn out [B,S,2048] bf16 32MB
#define OFF_VT   ((size_t)167772160)    // V^T bf16 [B,H,D,S] 32MB

extern "C" void kernel_launch(void* const* d_in, const int* in_sizes, int n_in,
                              void* d_out, int out_size, void* d_ws, size_t ws_size,
                              hipStream_t stream) {
  (void)in_sizes; (void)n_in; (void)out_size; (void)ws_size;
  const float* x    = (const float*)d_in[0];
  const float* wq   = (const float*)d_in[1];
  const float* wk   = (const float*)d_in[2];
  const float* wv   = (const float*)d_in[3];
  const float* wo   = (const float*)d_in[4];
  const float* cosT = (const float*)d_in[5];
  const float* sinT = (const float*)d_in[6];
  const int*   anc  = (const int*)d_in[7];
  float* out = (float*)d_out;
  char* ws = (char*)d_ws;

  bf16_t* xb   = (bf16_t*)(ws + OFF_XB);
  bf16_t* wcat = (bf16_t*)(ws + OFF_WCAT);
  bf16_t* wqt  = wcat;                              // rows 0..2047
  bf16_t* wkt  = wcat + (size_t)2048 * 2048;        // rows 2048..4095
  bf16_t* wvt  = wcat + (size_t)4096 * 2048;        // rows 4096..6143
  bf16_t* wot  = (bf16_t*)(ws + OFF_WOT);
  bf16_t* Qf   = (bf16_t*)(ws + OFF_QF);
  bf16_t* Kf   = (bf16_t*)(ws + OFF_KF);
  bf16_t* Vt   = (bf16_t*)(ws + OFF_VT);
  bf16_t* attnB = (bf16_t*)(ws + OFF_AT);

  cvt_f32_bf16<<<16384, 256, 0, stream>>>(x, xb);
  wtrans<<<dim3(32, 32), 256, 0, stream>>>(wq, wqt);
  wtrans<<<dim3(32, 32), 256, 0, stream>>>(wk, wkt);
  wtrans<<<dim3(32, 32), 256, 0, stream>>>(wv, wvt);
  wtrans<<<dim3(32, 32), 256, 0, stream>>>(wo, wot);
  // fused QKV projection + RoPE + V^T (grid 768 = 32 M-blocks x 24 N-blocks)
  gemm256<<<768, 512, 0, stream>>>(xb, wcat, 24, 1, nullptr, Qf, Kf, Vt, cosT, sinT);
  attn_kernel<<<1024, 512, 0, stream>>>(Qf, Kf, Vt, anc, attnB);
  // output projection (grid 256 = 32 x 8)
  gemm256<<<256, 512, 0, stream>>>(attnB, wot, 8, 0, out, nullptr, nullptr, nullptr,
                                   nullptr, nullptr);
}